// Round 3
// baseline (10515.416 us; speedup 1.0000x reference)
//
#include <hip/hip_runtime.h>
#include <math.h>

#define INP 256
#define HID 512
#define OUTD 256

__device__ __forceinline__ float gelu_f(float x) {
  // exact (erf) GELU, matches jax.nn.gelu(approximate=False)
  return 0.5f * x * (1.0f + erff(x * 0.7071067811865475f));
}

// ---------------- edge preprocessing ----------------

__global__ void hist_k(const int* __restrict__ col, int* __restrict__ cnt, int E) {
  int e = blockIdx.x * blockDim.x + threadIdx.x;
  if (e < E) atomicAdd(&cnt[col[e]], 1);
}

__global__ void dinv_k(const int* __restrict__ cnt, float* __restrict__ dinv, int n) {
  int i = blockIdx.x * blockDim.x + threadIdx.x;
  if (i < n) dinv[i] = rsqrtf((float)(cnt[i] + 1));  // +1 self-loop
}

__global__ void scan1_k(const int* __restrict__ cnt, int* __restrict__ offs,
                        int* __restrict__ bsum, int n) {
  __shared__ int s[256];
  int t = threadIdx.x;
  int i = blockIdx.x * 256 + t;
  int v = (i < n) ? cnt[i] : 0;
  s[t] = v;
  __syncthreads();
  #pragma unroll
  for (int off = 1; off < 256; off <<= 1) {
    int u = (t >= off) ? s[t - off] : 0;
    __syncthreads();
    s[t] += u;
    __syncthreads();
  }
  if (i < n) offs[i] = s[t] - v;          // exclusive within block
  if (t == 255) bsum[blockIdx.x] = s[255];
}

__global__ void scan2_k(int* __restrict__ bsum, int nb) {
  __shared__ int s[256];
  int t = threadIdx.x;
  int v = (t < nb) ? bsum[t] : 0;
  s[t] = v;
  __syncthreads();
  #pragma unroll
  for (int off = 1; off < 256; off <<= 1) {
    int u = (t >= off) ? s[t - off] : 0;
    __syncthreads();
    s[t] += u;
    __syncthreads();
  }
  if (t < nb) bsum[t] = s[t] - v;         // exclusive block offsets
}

__global__ void scan3_k(int* __restrict__ offs, const int* __restrict__ bsum, int n) {
  int i = blockIdx.x * 256 + threadIdx.x;
  if (i < n) offs[i] += bsum[blockIdx.x];
}

__global__ void scatter_k(const int* __restrict__ row, const int* __restrict__ col,
                          const int* __restrict__ offs, int* __restrict__ cur,
                          const float* __restrict__ dinv, int* __restrict__ srcs,
                          float* __restrict__ norms, int E) {
  int e = blockIdx.x * blockDim.x + threadIdx.x;
  if (e >= E) return;
  int r = row[e], c = col[e];
  int p = offs[c] + atomicAdd(&cur[c], 1);
  srcs[p] = r;
  norms[p] = dinv[r] * dinv[c];
}

// ---------------- fp32 tiled GEMM, prologue act on A, optional bias ----------------
// PRO: 0 = none, 1 = GELU, 2 = BN(scale,shift)+GELU.  C = act(A) @ B [+ bias]
template <int PRO, int BIAS>
__global__ __launch_bounds__(256) void gemm_k(
    const float* __restrict__ A, const float* __restrict__ B, float* __restrict__ C,
    int M, int K, int NN, const float* __restrict__ bias,
    const float* __restrict__ scale, const float* __restrict__ shift) {
  __shared__ float As[8][128];   // As[k][m] (transposed tile)
  __shared__ float Bs[8][128];
  const int t = threadIdx.x;
  const int bm = blockIdx.x * 128;
  const int bn = blockIdx.y * 128;
  const int tm = (t >> 4) << 3;          // 0..120
  const int tn = (t & 15) << 3;          // 0..120
  const int arow = t >> 1;               // 0..127
  const int acol = (t & 1) << 2;         // 0 or 4
  const int brow = t >> 5;               // 0..7
  const int bcol = (t & 31) << 2;        // 0..124
  const int gar = bm + arow;
  const bool aval = gar < M;
  const float* Ap = A + (size_t)gar * K + acol;
  const float* Bp = B + (size_t)brow * NN + bn + bcol;

  float acc[8][8];
  #pragma unroll
  for (int i = 0; i < 8; ++i)
    #pragma unroll
    for (int j = 0; j < 8; ++j) acc[i][j] = 0.f;

  for (int k0 = 0; k0 < K; k0 += 8) {
    float4 av = make_float4(0.f, 0.f, 0.f, 0.f);
    if (aval) av = *(const float4*)(Ap + k0);
    if (PRO == 2) {
      const float4 sc = *(const float4*)(scale + k0 + acol);
      const float4 sh = *(const float4*)(shift + k0 + acol);
      av.x = fmaf(av.x, sc.x, sh.x);
      av.y = fmaf(av.y, sc.y, sh.y);
      av.z = fmaf(av.z, sc.z, sh.z);
      av.w = fmaf(av.w, sc.w, sh.w);
    }
    if (PRO >= 1) {
      av.x = gelu_f(av.x); av.y = gelu_f(av.y);
      av.z = gelu_f(av.z); av.w = gelu_f(av.w);
    }
    float4 bv = *(const float4*)(Bp + (size_t)k0 * NN);
    As[acol + 0][arow] = av.x;
    As[acol + 1][arow] = av.y;
    As[acol + 2][arow] = av.z;
    As[acol + 3][arow] = av.w;
    *(float4*)(&Bs[brow][bcol]) = bv;
    __syncthreads();
    #pragma unroll
    for (int kk = 0; kk < 8; ++kk) {
      float4 a0 = *(const float4*)(&As[kk][tm]);
      float4 a1 = *(const float4*)(&As[kk][tm + 4]);
      float4 b0 = *(const float4*)(&Bs[kk][tn]);
      float4 b1 = *(const float4*)(&Bs[kk][tn + 4]);
      float a[8] = {a0.x, a0.y, a0.z, a0.w, a1.x, a1.y, a1.z, a1.w};
      float bb[8] = {b0.x, b0.y, b0.z, b0.w, b1.x, b1.y, b1.z, b1.w};
      #pragma unroll
      for (int i = 0; i < 8; ++i)
        #pragma unroll
        for (int j = 0; j < 8; ++j)
          acc[i][j] = fmaf(a[i], bb[j], acc[i][j]);
    }
    __syncthreads();
  }

  float4 c0 = make_float4(0.f, 0.f, 0.f, 0.f), c1 = c0;
  if (BIAS) {
    c0 = *(const float4*)(bias + bn + tn);
    c1 = *(const float4*)(bias + bn + tn + 4);
  }
  #pragma unroll
  for (int i = 0; i < 8; ++i) {
    int r = bm + tm + i;
    if (r < M) {
      float* Cp = C + (size_t)r * NN + bn + tn;
      float4 o0 = make_float4(acc[i][0] + c0.x, acc[i][1] + c0.y,
                              acc[i][2] + c0.z, acc[i][3] + c0.w);
      float4 o1 = make_float4(acc[i][4] + c1.x, acc[i][5] + c1.y,
                              acc[i][6] + c1.z, acc[i][7] + c1.w);
      *(float4*)(Cp) = o0;
      *(float4*)(Cp + 4) = o1;
    }
  }
}

// ---------------- CSC gather aggregation: one wave per target node ----------------
__global__ __launch_bounds__(256) void agg_k(
    const float* __restrict__ xw, const int* __restrict__ srcs,
    const float* __restrict__ norms, const int* __restrict__ offs,
    const int* __restrict__ cnt, const float* __restrict__ dinv,
    const float* __restrict__ bias, float* __restrict__ out, int n) {
  int wid = (blockIdx.x * blockDim.x + threadIdx.x) >> 6;  // wave id = node
  int lane = threadIdx.x & 63;
  if (wid >= n) return;
  const int base = offs[wid];
  const int num = cnt[wid];
  float4 a0 = make_float4(0.f, 0.f, 0.f, 0.f);
  float4 a1 = make_float4(0.f, 0.f, 0.f, 0.f);
  int k = 0;
  for (; k + 2 <= num; k += 2) {
    int s0 = srcs[base + k], s1 = srcs[base + k + 1];
    float w0 = norms[base + k], w1 = norms[base + k + 1];
    const float4* r0 = (const float4*)(xw + (size_t)s0 * HID);
    const float4* r1 = (const float4*)(xw + (size_t)s1 * HID);
    float4 x0 = r0[lane], y0 = r0[64 + lane];
    float4 x1 = r1[lane], y1 = r1[64 + lane];
    a0.x = fmaf(w0, x0.x, a0.x); a0.y = fmaf(w0, x0.y, a0.y);
    a0.z = fmaf(w0, x0.z, a0.z); a0.w = fmaf(w0, x0.w, a0.w);
    a1.x = fmaf(w0, y0.x, a1.x); a1.y = fmaf(w0, y0.y, a1.y);
    a1.z = fmaf(w0, y0.z, a1.z); a1.w = fmaf(w0, y0.w, a1.w);
    a0.x = fmaf(w1, x1.x, a0.x); a0.y = fmaf(w1, x1.y, a0.y);
    a0.z = fmaf(w1, x1.z, a0.z); a0.w = fmaf(w1, x1.w, a0.w);
    a1.x = fmaf(w1, y1.x, a1.x); a1.y = fmaf(w1, y1.y, a1.y);
    a1.z = fmaf(w1, y1.z, a1.z); a1.w = fmaf(w1, y1.w, a1.w);
  }
  if (k < num) {
    int s0 = srcs[base + k];
    float w0 = norms[base + k];
    const float4* r0 = (const float4*)(xw + (size_t)s0 * HID);
    float4 x0 = r0[lane], y0 = r0[64 + lane];
    a0.x = fmaf(w0, x0.x, a0.x); a0.y = fmaf(w0, x0.y, a0.y);
    a0.z = fmaf(w0, x0.z, a0.z); a0.w = fmaf(w0, x0.w, a0.w);
    a1.x = fmaf(w0, y0.x, a1.x); a1.y = fmaf(w0, y0.y, a1.y);
    a1.z = fmaf(w0, y0.z, a1.z); a1.w = fmaf(w0, y0.w, a1.w);
  }
  // self loop: norm = dinv[i]^2
  {
    float di = dinv[wid];
    float ws = di * di;
    const float4* rs = (const float4*)(xw + (size_t)wid * HID);
    float4 xs = rs[lane], ys = rs[64 + lane];
    a0.x = fmaf(ws, xs.x, a0.x); a0.y = fmaf(ws, xs.y, a0.y);
    a0.z = fmaf(ws, xs.z, a0.z); a0.w = fmaf(ws, xs.w, a0.w);
    a1.x = fmaf(ws, ys.x, a1.x); a1.y = fmaf(ws, ys.y, a1.y);
    a1.z = fmaf(ws, ys.z, a1.z); a1.w = fmaf(ws, ys.w, a1.w);
  }
  const float4 b0 = ((const float4*)bias)[lane];
  const float4 b1 = ((const float4*)bias)[64 + lane];
  a0.x += b0.x; a0.y += b0.y; a0.z += b0.z; a0.w += b0.w;
  a1.x += b1.x; a1.y += b1.y; a1.z += b1.z; a1.w += b1.w;
  float4* op = (float4*)(out + (size_t)wid * HID);
  op[lane] = a0;
  op[64 + lane] = a1;
}

// ---------------- BatchNorm (training-mode batch stats) ----------------
__global__ __launch_bounds__(512) void bn_stats_k(const float* __restrict__ F,
                                                  float* __restrict__ sums, int n) {
  int t = threadIdx.x;               // column 0..511
  int r0 = blockIdx.x * 128;
  int r1 = min(r0 + 128, n);
  float s = 0.f, s2 = 0.f;
  for (int r = r0; r < r1; ++r) {
    float v = F[(size_t)r * HID + t];
    s += v;
    s2 = fmaf(v, v, s2);
  }
  atomicAdd(&sums[t], s);
  atomicAdd(&sums[HID + t], s2);
}

__global__ void bn_fin_k(const float* __restrict__ sums, const float* __restrict__ g,
                         const float* __restrict__ b, float* __restrict__ scale,
                         float* __restrict__ shift, int n) {
  int t = threadIdx.x;
  float inv = 1.0f / (float)n;
  float mu = sums[t] * inv;
  float var = fmaf(-mu, mu, sums[HID + t] * inv);  // E[x^2]-mu^2 (biased, /N)
  float rs = rsqrtf(var + 1e-5f);
  float sc = g[t] * rs;
  scale[t] = sc;
  shift[t] = fmaf(-mu, sc, b[t]);
}

// ---------------- launch ----------------
// Workspace budget (crash theory: previous 322 MB carve overflowed ws_size):
//   d_ws : f0 (102.4 MB) + f1 (102.4 MB)                     = 204.8 MB
//   d_out: srcs/norms/cnt/cur/offs/bsum/dinv/bn scratch      =  ~13.5 MB
// d_out scratch is legal: every reader (hist..agg/bn) precedes the final
// output GEMM in stream order, and that GEMM overwrites all of d_out.
extern "C" void kernel_launch(void* const* d_in, const int* in_sizes, int n_in,
                              void* d_out, int out_size, void* d_ws, size_t ws_size,
                              hipStream_t stream) {
  const float* x     = (const float*)d_in[0];
  const int*   ei    = (const int*)d_in[1];
  const float* Wf    = (const float*)d_in[2];
  const float* bf    = (const float*)d_in[3];
  const float* Wr    = (const float*)d_in[4];
  const float* br    = (const float*)d_in[5];
  const float* gamma = (const float*)d_in[6];
  const float* beta  = (const float*)d_in[7];
  const float* Wo    = (const float*)d_in[8];
  const float* bo    = (const float*)d_in[9];
  float* out = (float*)d_out;

  const int n = in_sizes[0] / INP;
  const int E = in_sizes[1] / 2;
  const int* erow = ei;
  const int* ecol = ei + E;

  // feature ping-pong buffers in d_ws (the ONLY d_ws usage)
  char* w = (char*)d_ws;
  float* f0 = (float*)w; w += (size_t)n * HID * sizeof(float);
  float* f1 = (float*)w; w += (size_t)n * HID * sizeof(float);

  // small scratch carved from d_out (overwritten by the final GEMM at the end)
  char* q = (char*)d_out;
  int*   srcs  = (int*)q;   q += (size_t)E * sizeof(int);
  float* norms = (float*)q; q += (size_t)E * sizeof(float);
  int*   cnt   = (int*)q;   q += (size_t)n * sizeof(int);
  int*   cur   = (int*)q;   q += (size_t)n * sizeof(int);
  int*   offs  = (int*)q;   q += (size_t)n * sizeof(int);
  int*   bsum  = (int*)q;   q += 256 * sizeof(int);
  float* dinv  = (float*)q; q += (size_t)n * sizeof(float);
  float* bnsum = (float*)q; q += 1024 * sizeof(float);
  float* bnsc  = (float*)q; q += 512 * sizeof(float);
  float* bnsh  = (float*)q; q += 512 * sizeof(float);

  hipMemsetAsync(cnt, 0, (size_t)n * sizeof(int), stream);
  hipMemsetAsync(cur, 0, (size_t)n * sizeof(int), stream);

  const int eb = (E + 255) / 256;
  const int nb = (n + 255) / 256;
  hist_k<<<eb, 256, 0, stream>>>(ecol, cnt, E);
  dinv_k<<<nb, 256, 0, stream>>>(cnt, dinv, n);
  scan1_k<<<nb, 256, 0, stream>>>(cnt, offs, bsum, n);
  scan2_k<<<1, 256, 0, stream>>>(bsum, nb);
  scan3_k<<<nb, 256, 0, stream>>>(offs, bsum, n);
  scatter_k<<<eb, 256, 0, stream>>>(erow, ecol, offs, cur, dinv, srcs, norms, E);

  const dim3 blk(256);
  const int mg = (n + 127) / 128;
  const dim3 g512(mg, HID / 128);
  const dim3 g256(mg, OUTD / 128);
  const int aggBlocks = (n + 3) / 4;  // 1 wave/node, 4 waves/block

  // conv: GEMM in->f1 (prologue act), then agg f1->f0
  auto conv = [&](const float* in, const float* W, const float* b, int K, int pro) {
    if (pro == 0)
      gemm_k<0, 0><<<g512, blk, 0, stream>>>(in, W, f1, n, K, HID, nullptr, nullptr, nullptr);
    else if (pro == 1)
      gemm_k<1, 0><<<g512, blk, 0, stream>>>(in, W, f1, n, K, HID, nullptr, nullptr, nullptr);
    else
      gemm_k<2, 0><<<g512, blk, 0, stream>>>(in, W, f1, n, K, HID, nullptr, bnsc, bnsh);
    agg_k<<<aggBlocks, blk, 0, stream>>>(f1, srcs, norms, offs, cnt, dinv, b, f0, n);
  };
  auto bn = [&](const float* F, int g) {
    hipMemsetAsync(bnsum, 0, 1024 * sizeof(float), stream);
    bn_stats_k<<<(n + 127) / 128, 512, 0, stream>>>(F, bnsum, n);
    bn_fin_k<<<1, 512, 0, stream>>>(bnsum, gamma + (size_t)g * HID,
                                    beta + (size_t)g * HID, bnsc, bnsh, n);
  };
  const size_t WS = (size_t)HID * HID;

  conv(x,  Wf,           bf,            INP, 0);   // conv1
  conv(f0, Wr + 0 * WS,  br + 0 * HID,  HID, 1);   // conv2
  conv(f0, Wr + 1 * WS,  br + 1 * HID,  HID, 1);   // conv3
  conv(f0, Wr + 2 * WS,  br + 2 * HID,  HID, 0);   // conv4 (no act)
  conv(f0, Wr + 3 * WS,  br + 3 * HID,  HID, 1);   // conv5
  conv(f0, Wr + 4 * WS,  br + 4 * HID,  HID, 1);   // conv6
  bn(f0, 0);                                       // BN block 0
  conv(f0, Wr + 5 * WS,  br + 5 * HID,  HID, 2);   // conv7 (bn+gelu prologue)
  conv(f0, Wr + 6 * WS,  br + 6 * HID,  HID, 1);   // conv8
  conv(f0, Wr + 7 * WS,  br + 7 * HID,  HID, 1);   // conv9
  bn(f0, 1);                                       // BN block 1
  conv(f0, Wr + 8 * WS,  br + 8 * HID,  HID, 2);   // conv10
  conv(f0, Wr + 9 * WS,  br + 9 * HID,  HID, 1);   // conv11
  conv(f0, Wr + 10 * WS, br + 10 * HID, HID, 1);   // conv12
  gemm_k<0, 1><<<g256, blk, 0, stream>>>(f0, Wo, out, n, HID, OUTD, bo, nullptr, nullptr);
}

// Round 4
// 10223.550 us; speedup vs baseline: 1.0285x; 1.0285x over previous
//
#include <hip/hip_runtime.h>
#include <math.h>

#define INP 256
#define HID 512
#define OUTD 256

__device__ __forceinline__ float gelu_f(float x) {
  // exact (erf) GELU, matches jax.nn.gelu(approximate=False)
  return 0.5f * x * (1.0f + erff(x * 0.7071067811865475f));
}

__device__ __forceinline__ void fma4(float4& a, float w, const float4& x) {
  a.x = fmaf(w, x.x, a.x);
  a.y = fmaf(w, x.y, a.y);
  a.z = fmaf(w, x.z, a.z);
  a.w = fmaf(w, x.w, a.w);
}

// ---------------- edge preprocessing ----------------

__global__ void hist_k(const int* __restrict__ col, int* __restrict__ cnt, int E) {
  int e = blockIdx.x * blockDim.x + threadIdx.x;
  if (e < E) atomicAdd(&cnt[col[e]], 1);
}

__global__ void dinv_k(const int* __restrict__ cnt, float* __restrict__ dinv, int n) {
  int i = blockIdx.x * blockDim.x + threadIdx.x;
  if (i < n) dinv[i] = rsqrtf((float)(cnt[i] + 1));  // +1 self-loop
}

__global__ void scan1_k(const int* __restrict__ cnt, int* __restrict__ offs,
                        int* __restrict__ bsum, int n) {
  __shared__ int s[256];
  int t = threadIdx.x;
  int i = blockIdx.x * 256 + t;
  int v = (i < n) ? cnt[i] : 0;
  s[t] = v;
  __syncthreads();
  #pragma unroll
  for (int off = 1; off < 256; off <<= 1) {
    int u = (t >= off) ? s[t - off] : 0;
    __syncthreads();
    s[t] += u;
    __syncthreads();
  }
  if (i < n) offs[i] = s[t] - v;          // exclusive within block
  if (t == 255) bsum[blockIdx.x] = s[255];
}

__global__ void scan2_k(int* __restrict__ bsum, int nb) {
  __shared__ int s[256];
  int t = threadIdx.x;
  int v = (t < nb) ? bsum[t] : 0;
  s[t] = v;
  __syncthreads();
  #pragma unroll
  for (int off = 1; off < 256; off <<= 1) {
    int u = (t >= off) ? s[t - off] : 0;
    __syncthreads();
    s[t] += u;
    __syncthreads();
  }
  if (t < nb) bsum[t] = s[t] - v;         // exclusive block offsets
}

__global__ void scan3_k(int* __restrict__ offs, const int* __restrict__ bsum, int n) {
  int i = blockIdx.x * 256 + threadIdx.x;
  if (i < n) offs[i] += bsum[blockIdx.x];
}

__global__ void scatter_k(const int* __restrict__ row, const int* __restrict__ col,
                          const int* __restrict__ offs, int* __restrict__ cur,
                          const float* __restrict__ dinv, int* __restrict__ srcs,
                          float* __restrict__ norms, int E) {
  int e = blockIdx.x * blockDim.x + threadIdx.x;
  if (e >= E) return;
  int r = row[e], c = col[e];
  int p = offs[c] + atomicAdd(&cur[c], 1);
  srcs[p] = r;
  norms[p] = dinv[r] * dinv[c];
}

// ---------------- fp32 tiled GEMM, prologue act on A, optional bias ----------------
// PRO: 0 = none, 1 = GELU, 2 = BN(scale,shift)+GELU.  C = act(A) @ B [+ bias]
template <int PRO, int BIAS>
__global__ __launch_bounds__(256) void gemm_k(
    const float* __restrict__ A, const float* __restrict__ B, float* __restrict__ C,
    int M, int K, int NN, const float* __restrict__ bias,
    const float* __restrict__ scale, const float* __restrict__ shift) {
  __shared__ float As[8][128];   // As[k][m] (transposed tile)
  __shared__ float Bs[8][128];
  const int t = threadIdx.x;
  const int bm = blockIdx.x * 128;
  const int bn = blockIdx.y * 128;
  const int tm = (t >> 4) << 3;          // 0..120
  const int tn = (t & 15) << 3;          // 0..120
  const int arow = t >> 1;               // 0..127
  const int acol = (t & 1) << 2;         // 0 or 4
  const int brow = t >> 5;               // 0..7
  const int bcol = (t & 31) << 2;        // 0..124
  const int gar = bm + arow;
  const bool aval = gar < M;
  const float* Ap = A + (size_t)gar * K + acol;
  const float* Bp = B + (size_t)brow * NN + bn + bcol;

  float acc[8][8];
  #pragma unroll
  for (int i = 0; i < 8; ++i)
    #pragma unroll
    for (int j = 0; j < 8; ++j) acc[i][j] = 0.f;

  for (int k0 = 0; k0 < K; k0 += 8) {
    float4 av = make_float4(0.f, 0.f, 0.f, 0.f);
    if (aval) av = *(const float4*)(Ap + k0);
    if (PRO == 2) {
      const float4 sc = *(const float4*)(scale + k0 + acol);
      const float4 sh = *(const float4*)(shift + k0 + acol);
      av.x = fmaf(av.x, sc.x, sh.x);
      av.y = fmaf(av.y, sc.y, sh.y);
      av.z = fmaf(av.z, sc.z, sh.z);
      av.w = fmaf(av.w, sc.w, sh.w);
    }
    if (PRO >= 1) {
      av.x = gelu_f(av.x); av.y = gelu_f(av.y);
      av.z = gelu_f(av.z); av.w = gelu_f(av.w);
    }
    float4 bv = *(const float4*)(Bp + (size_t)k0 * NN);
    As[acol + 0][arow] = av.x;
    As[acol + 1][arow] = av.y;
    As[acol + 2][arow] = av.z;
    As[acol + 3][arow] = av.w;
    *(float4*)(&Bs[brow][bcol]) = bv;
    __syncthreads();
    #pragma unroll
    for (int kk = 0; kk < 8; ++kk) {
      float4 a0 = *(const float4*)(&As[kk][tm]);
      float4 a1 = *(const float4*)(&As[kk][tm + 4]);
      float4 b0 = *(const float4*)(&Bs[kk][tn]);
      float4 b1 = *(const float4*)(&Bs[kk][tn + 4]);
      float a[8] = {a0.x, a0.y, a0.z, a0.w, a1.x, a1.y, a1.z, a1.w};
      float bb[8] = {b0.x, b0.y, b0.z, b0.w, b1.x, b1.y, b1.z, b1.w};
      #pragma unroll
      for (int i = 0; i < 8; ++i)
        #pragma unroll
        for (int j = 0; j < 8; ++j)
          acc[i][j] = fmaf(a[i], bb[j], acc[i][j]);
    }
    __syncthreads();
  }

  float4 c0 = make_float4(0.f, 0.f, 0.f, 0.f), c1 = c0;
  if (BIAS) {
    c0 = *(const float4*)(bias + bn + tn);
    c1 = *(const float4*)(bias + bn + tn + 4);
  }
  #pragma unroll
  for (int i = 0; i < 8; ++i) {
    int r = bm + tm + i;
    if (r < M) {
      float* Cp = C + (size_t)r * NN + bn + tn;
      float4 o0 = make_float4(acc[i][0] + c0.x, acc[i][1] + c0.y,
                              acc[i][2] + c0.z, acc[i][3] + c0.w);
      float4 o1 = make_float4(acc[i][4] + c1.x, acc[i][5] + c1.y,
                              acc[i][6] + c1.z, acc[i][7] + c1.w);
      *(float4*)(Cp) = o0;
      *(float4*)(Cp + 4) = o1;
    }
  }
}

// ---------------- CSC gather aggregation: one wave per target node ----------------
// Software-pipelined 4-edge windows: indices for window k+1 load concurrently
// with the row gathers of window k (breaks the idx->addr->row serial chain).
// D = feature dim (256 or 512). bias==nullptr -> no bias.
template <int D>
__global__ __launch_bounds__(256) void agg_k(
    const float* __restrict__ xw, const int* __restrict__ srcs,
    const float* __restrict__ norms, const int* __restrict__ offs,
    const int* __restrict__ cnt, const float* __restrict__ dinv,
    const float* __restrict__ bias, float* __restrict__ out, int n) {
  constexpr int NV = D / 256;  // float4s per lane
  int wid = (blockIdx.x * blockDim.x + threadIdx.x) >> 6;  // wave id = node
  int lane = threadIdx.x & 63;
  if (wid >= n) return;
  const int base = offs[wid];
  const int num = cnt[wid];

  float4 acc[NV];
  #pragma unroll
  for (int v = 0; v < NV; ++v) acc[v] = make_float4(0.f, 0.f, 0.f, 0.f);

  int sA[4];
  float wA[4];
  #pragma unroll
  for (int j = 0; j < 4; ++j) {
    bool ok = j < num;
    sA[j] = ok ? srcs[base + j] : 0;
    wA[j] = ok ? norms[base + j] : 0.f;
  }

  for (int k0 = 0; k0 < num; k0 += 4) {
    // issue 4 row gathers (masked tail edges read row 0 with weight 0)
    float4 r[4][NV];
    #pragma unroll
    for (int j = 0; j < 4; ++j) {
      const float4* rp = (const float4*)(xw + (size_t)sA[j] * D);
      #pragma unroll
      for (int v = 0; v < NV; ++v) r[j][v] = rp[v * 64 + lane];
    }
    // prefetch next window's indices while the gathers are in flight
    int sB[4];
    float wB[4];
    #pragma unroll
    for (int j = 0; j < 4; ++j) {
      int e = k0 + 4 + j;
      bool ok = e < num;
      sB[j] = ok ? srcs[base + e] : 0;
      wB[j] = ok ? norms[base + e] : 0.f;
    }
    #pragma unroll
    for (int j = 0; j < 4; ++j)
      #pragma unroll
      for (int v = 0; v < NV; ++v) fma4(acc[v], wA[j], r[j][v]);
    #pragma unroll
    for (int j = 0; j < 4; ++j) { sA[j] = sB[j]; wA[j] = wB[j]; }
  }

  // self loop: norm = dinv[i]^2
  {
    float di = dinv[wid];
    float ws = di * di;
    const float4* rs = (const float4*)(xw + (size_t)wid * D);
    #pragma unroll
    for (int v = 0; v < NV; ++v) {
      float4 xs = rs[v * 64 + lane];
      fma4(acc[v], ws, xs);
    }
  }
  if (bias) {
    #pragma unroll
    for (int v = 0; v < NV; ++v) {
      float4 b = ((const float4*)bias)[v * 64 + lane];
      acc[v].x += b.x; acc[v].y += b.y; acc[v].z += b.z; acc[v].w += b.w;
    }
  }
  float4* op = (float4*)(out + (size_t)wid * D);
  #pragma unroll
  for (int v = 0; v < NV; ++v) op[v * 64 + lane] = acc[v];
}

// ---------------- BatchNorm (training-mode batch stats) ----------------
__global__ __launch_bounds__(512) void bn_stats_k(const float* __restrict__ F,
                                                  float* __restrict__ sums, int n) {
  int t = threadIdx.x;               // column 0..511
  int r0 = blockIdx.x * 128;
  int r1 = min(r0 + 128, n);
  float s = 0.f, s2 = 0.f;
  for (int r = r0; r < r1; ++r) {
    float v = F[(size_t)r * HID + t];
    s += v;
    s2 = fmaf(v, v, s2);
  }
  atomicAdd(&sums[t], s);
  atomicAdd(&sums[HID + t], s2);
}

__global__ void bn_fin_k(const float* __restrict__ sums, const float* __restrict__ g,
                         const float* __restrict__ b, float* __restrict__ scale,
                         float* __restrict__ shift, int n) {
  int t = threadIdx.x;
  float inv = 1.0f / (float)n;
  float mu = sums[t] * inv;
  float var = fmaf(-mu, mu, sums[HID + t] * inv);  // E[x^2]-mu^2 (biased, /N)
  float rs = rsqrtf(var + 1e-5f);
  float sc = g[t] * rs;
  scale[t] = sc;
  shift[t] = fmaf(-mu, sc, b[t]);
}

// ---------------- launch ----------------
// Workspace budget:
//   d_ws : f0 (102.4 MB) + f1 (102.4 MB)                     = 204.8 MB
//   d_out: srcs/norms/cnt/cur/offs/bsum/dinv/bn scratch      =  ~13.5 MB
// d_out scratch is legal: every reader (hist..agg/bn) precedes the final
// output GEMM in stream order, and that GEMM overwrites all of d_out.
extern "C" void kernel_launch(void* const* d_in, const int* in_sizes, int n_in,
                              void* d_out, int out_size, void* d_ws, size_t ws_size,
                              hipStream_t stream) {
  const float* x     = (const float*)d_in[0];
  const int*   ei    = (const int*)d_in[1];
  const float* Wf    = (const float*)d_in[2];
  const float* bf    = (const float*)d_in[3];
  const float* Wr    = (const float*)d_in[4];
  const float* br    = (const float*)d_in[5];
  const float* gamma = (const float*)d_in[6];
  const float* beta  = (const float*)d_in[7];
  const float* Wo    = (const float*)d_in[8];
  const float* bo    = (const float*)d_in[9];
  float* out = (float*)d_out;

  const int n = in_sizes[0] / INP;
  const int E = in_sizes[1] / 2;
  const int* erow = ei;
  const int* ecol = ei + E;

  // feature ping-pong buffers in d_ws (the ONLY d_ws usage)
  char* w = (char*)d_ws;
  float* f0 = (float*)w; w += (size_t)n * HID * sizeof(float);
  float* f1 = (float*)w; w += (size_t)n * HID * sizeof(float);

  // small scratch carved from d_out (overwritten by the final GEMM at the end)
  char* q = (char*)d_out;
  int*   srcs  = (int*)q;   q += (size_t)E * sizeof(int);
  float* norms = (float*)q; q += (size_t)E * sizeof(float);
  int*   cnt   = (int*)q;   q += (size_t)n * sizeof(int);
  int*   cur   = (int*)q;   q += (size_t)n * sizeof(int);
  int*   offs  = (int*)q;   q += (size_t)n * sizeof(int);
  int*   bsum  = (int*)q;   q += 256 * sizeof(int);
  float* dinv  = (float*)q; q += (size_t)n * sizeof(float);
  float* bnsum = (float*)q; q += 1024 * sizeof(float);
  float* bnsc  = (float*)q; q += 512 * sizeof(float);
  float* bnsh  = (float*)q; q += 512 * sizeof(float);

  hipMemsetAsync(cnt, 0, (size_t)n * sizeof(int), stream);
  hipMemsetAsync(cur, 0, (size_t)n * sizeof(int), stream);

  const int eb = (E + 255) / 256;
  const int nb = (n + 255) / 256;
  hist_k<<<eb, 256, 0, stream>>>(ecol, cnt, E);
  dinv_k<<<nb, 256, 0, stream>>>(cnt, dinv, n);
  scan1_k<<<nb, 256, 0, stream>>>(cnt, offs, bsum, n);
  scan2_k<<<1, 256, 0, stream>>>(bsum, nb);
  scan3_k<<<nb, 256, 0, stream>>>(offs, bsum, n);
  scatter_k<<<eb, 256, 0, stream>>>(erow, ecol, offs, cur, dinv, srcs, norms, E);

  const dim3 blk(256);
  const int mg = (n + 127) / 128;
  const dim3 g512(mg, HID / 128);
  const dim3 g256(mg, OUTD / 128);
  const int aggBlocks = (n + 3) / 4;  // 1 wave/node, 4 waves/block

  // conv2..12: GEMM f0->f1 (prologue act), then agg f1->f0 (bias epilogue)
  auto conv = [&](const float* W, const float* b, int pro) {
    if (pro == 1)
      gemm_k<1, 0><<<g512, blk, 0, stream>>>(f0, W, f1, n, HID, HID, nullptr, nullptr, nullptr);
    else if (pro == 2)
      gemm_k<2, 0><<<g512, blk, 0, stream>>>(f0, W, f1, n, HID, HID, nullptr, bnsc, bnsh);
    else
      gemm_k<0, 0><<<g512, blk, 0, stream>>>(f0, W, f1, n, HID, HID, nullptr, nullptr, nullptr);
    agg_k<HID><<<aggBlocks, blk, 0, stream>>>(f1, srcs, norms, offs, cnt, dinv, b, f0, n);
  };
  auto bn = [&](const float* F, int g) {
    hipMemsetAsync(bnsum, 0, 1024 * sizeof(float), stream);
    bn_stats_k<<<(n + 127) / 128, 512, 0, stream>>>(F, bnsum, n);
    bn_fin_k<<<1, 512, 0, stream>>>(bnsum, gamma + (size_t)g * HID,
                                    beta + (size_t)g * HID, bnsc, bnsh, n);
  };
  const size_t WS = (size_t)HID * HID;

  // conv1 reordered: A(xW)+b == (Ax)W + b — aggregate at 256 dims first
  // (halves conv1 gather traffic), bias lands in the GEMM epilogue.
  agg_k<INP><<<aggBlocks, blk, 0, stream>>>(x, srcs, norms, offs, cnt, dinv,
                                            nullptr, f1, n);
  gemm_k<0, 1><<<g512, blk, 0, stream>>>(f1, Wf, f0, n, INP, HID, bf, nullptr, nullptr);

  conv(Wr + 0 * WS,  br + 0 * HID,  1);   // conv2
  conv(Wr + 1 * WS,  br + 1 * HID,  1);   // conv3
  conv(Wr + 2 * WS,  br + 2 * HID,  0);   // conv4 (no act)
  conv(Wr + 3 * WS,  br + 3 * HID,  1);   // conv5
  conv(Wr + 4 * WS,  br + 4 * HID,  1);   // conv6
  bn(f0, 0);                              // BN block 0
  conv(Wr + 5 * WS,  br + 5 * HID,  2);   // conv7 (bn+gelu prologue)
  conv(Wr + 6 * WS,  br + 6 * HID,  1);   // conv8
  conv(Wr + 7 * WS,  br + 7 * HID,  1);   // conv9
  bn(f0, 1);                              // BN block 1
  conv(Wr + 8 * WS,  br + 8 * HID,  2);   // conv10
  conv(Wr + 9 * WS,  br + 9 * HID,  1);   // conv11
  conv(Wr + 10 * WS, br + 10 * HID, 1);   // conv12
  gemm_k<0, 1><<<g256, blk, 0, stream>>>(f0, Wo, out, n, HID, OUTD, bo, nullptr, nullptr);
}

// Round 5
// 9863.223 us; speedup vs baseline: 1.0661x; 1.0365x over previous
//
#include <hip/hip_runtime.h>
#include <math.h>

#define INP 256
#define HID 512
#define OUTD 256

__device__ __forceinline__ float gelu_f(float x) {
  // exact (erf) GELU, matches jax.nn.gelu(approximate=False)
  return 0.5f * x * (1.0f + erff(x * 0.7071067811865475f));
}

__device__ __forceinline__ void fma4(float4& a, float w, const float4& x) {
  a.x = fmaf(w, x.x, a.x);
  a.y = fmaf(w, x.y, a.y);
  a.z = fmaf(w, x.z, a.z);
  a.w = fmaf(w, x.w, a.w);
}

// ---------------- edge preprocessing ----------------

__global__ void hist_k(const int* __restrict__ col, int* __restrict__ cnt, int E) {
  int e = blockIdx.x * blockDim.x + threadIdx.x;
  if (e < E) atomicAdd(&cnt[col[e]], 1);
}

__global__ void dinv_k(const int* __restrict__ cnt, float* __restrict__ dinv, int n) {
  int i = blockIdx.x * blockDim.x + threadIdx.x;
  if (i < n) dinv[i] = rsqrtf((float)(cnt[i] + 1));  // +1 self-loop
}

__global__ void scan1_k(const int* __restrict__ cnt, int* __restrict__ offs,
                        int* __restrict__ bsum, int n) {
  __shared__ int s[256];
  int t = threadIdx.x;
  int i = blockIdx.x * 256 + t;
  int v = (i < n) ? cnt[i] : 0;
  s[t] = v;
  __syncthreads();
  #pragma unroll
  for (int off = 1; off < 256; off <<= 1) {
    int u = (t >= off) ? s[t - off] : 0;
    __syncthreads();
    s[t] += u;
    __syncthreads();
  }
  if (i < n) offs[i] = s[t] - v;          // exclusive within block
  if (t == 255) bsum[blockIdx.x] = s[255];
}

__global__ void scan2_k(int* __restrict__ bsum, int nb) {
  __shared__ int s[256];
  int t = threadIdx.x;
  int v = (t < nb) ? bsum[t] : 0;
  s[t] = v;
  __syncthreads();
  #pragma unroll
  for (int off = 1; off < 256; off <<= 1) {
    int u = (t >= off) ? s[t - off] : 0;
    __syncthreads();
    s[t] += u;
    __syncthreads();
  }
  if (t < nb) bsum[t] = s[t] - v;         // exclusive block offsets
}

__global__ void scan3_k(int* __restrict__ offs, const int* __restrict__ bsum, int n) {
  int i = blockIdx.x * 256 + threadIdx.x;
  if (i < n) offs[i] += bsum[blockIdx.x];
}

__global__ void scatter_k(const int* __restrict__ row, const int* __restrict__ col,
                          const int* __restrict__ offs, int* __restrict__ cur,
                          const float* __restrict__ dinv, int* __restrict__ srcs,
                          float* __restrict__ norms, int E) {
  int e = blockIdx.x * blockDim.x + threadIdx.x;
  if (e >= E) return;
  int r = row[e], c = col[e];
  int p = offs[c] + atomicAdd(&cur[c], 1);
  srcs[p] = r;
  norms[p] = dinv[r] * dinv[c];
}

// ---------------- fp32 tiled GEMM, prologue act on A, optional bias ----------------
// PRO: 0 = none, 1 = GELU, 2 = BN(scale,shift)+GELU.  C = act(A) @ B [+ bias]
template <int PRO, int BIAS>
__global__ __launch_bounds__(256) void gemm_k(
    const float* __restrict__ A, const float* __restrict__ B, float* __restrict__ C,
    int M, int K, int NN, const float* __restrict__ bias,
    const float* __restrict__ scale, const float* __restrict__ shift) {
  __shared__ float As[8][128];   // As[k][m] (transposed tile)
  __shared__ float Bs[8][128];
  const int t = threadIdx.x;
  const int bm = blockIdx.x * 128;
  const int bn = blockIdx.y * 128;
  const int tm = (t >> 4) << 3;          // 0..120
  const int tn = (t & 15) << 3;          // 0..120
  const int arow = t >> 1;               // 0..127
  const int acol = (t & 1) << 2;         // 0 or 4
  const int brow = t >> 5;               // 0..7
  const int bcol = (t & 31) << 2;        // 0..124
  const int gar = bm + arow;
  const bool aval = gar < M;
  const float* Ap = A + (size_t)gar * K + acol;
  const float* Bp = B + (size_t)brow * NN + bn + bcol;

  float acc[8][8];
  #pragma unroll
  for (int i = 0; i < 8; ++i)
    #pragma unroll
    for (int j = 0; j < 8; ++j) acc[i][j] = 0.f;

  for (int k0 = 0; k0 < K; k0 += 8) {
    float4 av = make_float4(0.f, 0.f, 0.f, 0.f);
    if (aval) av = *(const float4*)(Ap + k0);
    if (PRO == 2) {
      const float4 sc = *(const float4*)(scale + k0 + acol);
      const float4 sh = *(const float4*)(shift + k0 + acol);
      av.x = fmaf(av.x, sc.x, sh.x);
      av.y = fmaf(av.y, sc.y, sh.y);
      av.z = fmaf(av.z, sc.z, sh.z);
      av.w = fmaf(av.w, sc.w, sh.w);
    }
    if (PRO >= 1) {
      av.x = gelu_f(av.x); av.y = gelu_f(av.y);
      av.z = gelu_f(av.z); av.w = gelu_f(av.w);
    }
    float4 bv = *(const float4*)(Bp + (size_t)k0 * NN);
    As[acol + 0][arow] = av.x;
    As[acol + 1][arow] = av.y;
    As[acol + 2][arow] = av.z;
    As[acol + 3][arow] = av.w;
    *(float4*)(&Bs[brow][bcol]) = bv;
    __syncthreads();
    #pragma unroll
    for (int kk = 0; kk < 8; ++kk) {
      float4 a0 = *(const float4*)(&As[kk][tm]);
      float4 a1 = *(const float4*)(&As[kk][tm + 4]);
      float4 b0 = *(const float4*)(&Bs[kk][tn]);
      float4 b1 = *(const float4*)(&Bs[kk][tn + 4]);
      float a[8] = {a0.x, a0.y, a0.z, a0.w, a1.x, a1.y, a1.z, a1.w};
      float bb[8] = {b0.x, b0.y, b0.z, b0.w, b1.x, b1.y, b1.z, b1.w};
      #pragma unroll
      for (int i = 0; i < 8; ++i)
        #pragma unroll
        for (int j = 0; j < 8; ++j)
          acc[i][j] = fmaf(a[i], bb[j], acc[i][j]);
    }
    __syncthreads();
  }

  float4 c0 = make_float4(0.f, 0.f, 0.f, 0.f), c1 = c0;
  if (BIAS) {
    c0 = *(const float4*)(bias + bn + tn);
    c1 = *(const float4*)(bias + bn + tn + 4);
  }
  #pragma unroll
  for (int i = 0; i < 8; ++i) {
    int r = bm + tm + i;
    if (r < M) {
      float* Cp = C + (size_t)r * NN + bn + tn;
      float4 o0 = make_float4(acc[i][0] + c0.x, acc[i][1] + c0.y,
                              acc[i][2] + c0.z, acc[i][3] + c0.w);
      float4 o1 = make_float4(acc[i][4] + c1.x, acc[i][5] + c1.y,
                              acc[i][6] + c1.z, acc[i][7] + c1.w);
      *(float4*)(Cp) = o0;
      *(float4*)(Cp + 4) = o1;
    }
  }
}

// ---------------- CSC gather aggregation: one wave per target node ----------------
// Register double-buffered 4-edge windows: window k+1's EIGHT 1KB row loads are
// ISSUED before window k is consumed, so per-register vmcnt scoreboarding keeps
// 8KB/wave in flight continuously (round-4 counters showed ~0.8KB/wave: VGPR=36
// proved the compiler collapsed the window; this version pins rA+rB = 64 VGPRs).
// D = feature dim (256 or 512). bias==nullptr -> no bias.
template <int D>
__global__ __launch_bounds__(256) void agg_k(
    const float* __restrict__ xw, const int* __restrict__ srcs,
    const float* __restrict__ norms, const int* __restrict__ offs,
    const int* __restrict__ cnt, const float* __restrict__ dinv,
    const float* __restrict__ bias, float* __restrict__ out, int n) {
  constexpr int NV = D / 256;  // float4s per lane per row
  int wid = (blockIdx.x * blockDim.x + threadIdx.x) >> 6;  // wave id = node
  int lane = threadIdx.x & 63;
  if (wid >= n) return;
  const int base = offs[wid];
  const int num = cnt[wid];

  float4 acc[NV];
  #pragma unroll
  for (int v = 0; v < NV; ++v) acc[v] = make_float4(0.f, 0.f, 0.f, 0.f);

  int sA[4], sB[4];
  float wA[4], wB[4];
  float4 rA[4][NV], rB[4][NV];

  auto ldidx = [&](int e, int& s, float& w) {
    bool ok = e < num;
    s = ok ? srcs[base + e] : 0;       // masked edges -> row 0, weight 0
    w = ok ? norms[base + e] : 0.f;
  };

  const int nw = (num + 3) >> 2;  // 4-edge windows

  if (nw > 0) {
    // prologue: window 0 -> rA
    #pragma unroll
    for (int j = 0; j < 4; ++j) ldidx(j, sA[j], wA[j]);
    #pragma unroll
    for (int j = 0; j < 4; ++j) {
      const float4* rp = (const float4*)(xw + (size_t)sA[j] * D);
      #pragma unroll
      for (int v = 0; v < NV; ++v) rA[j][v] = rp[v * 64 + lane];
    }

    int w = 0;
    for (; w + 2 <= nw; w += 2) {
      // issue window w+1 -> rB (8KB in flight while consuming rA)
      #pragma unroll
      for (int j = 0; j < 4; ++j) ldidx((w + 1) * 4 + j, sB[j], wB[j]);
      #pragma unroll
      for (int j = 0; j < 4; ++j) {
        const float4* rp = (const float4*)(xw + (size_t)sB[j] * D);
        #pragma unroll
        for (int v = 0; v < NV; ++v) rB[j][v] = rp[v * 64 + lane];
      }
      // consume window w (rA)
      #pragma unroll
      for (int j = 0; j < 4; ++j)
        #pragma unroll
        for (int v = 0; v < NV; ++v) fma4(acc[v], wA[j], rA[j][v]);
      // issue window w+2 -> rA (if any)
      if (w + 2 < nw) {
        #pragma unroll
        for (int j = 0; j < 4; ++j) ldidx((w + 2) * 4 + j, sA[j], wA[j]);
        #pragma unroll
        for (int j = 0; j < 4; ++j) {
          const float4* rp = (const float4*)(xw + (size_t)sA[j] * D);
          #pragma unroll
          for (int v = 0; v < NV; ++v) rA[j][v] = rp[v * 64 + lane];
        }
      }
      // consume window w+1 (rB)
      #pragma unroll
      for (int j = 0; j < 4; ++j)
        #pragma unroll
        for (int v = 0; v < NV; ++v) fma4(acc[v], wB[j], rB[j][v]);
    }
    if (w < nw) {  // odd window count: last window is parked in rA
      #pragma unroll
      for (int j = 0; j < 4; ++j)
        #pragma unroll
        for (int v = 0; v < NV; ++v) fma4(acc[v], wA[j], rA[j][v]);
    }
  }

  // self loop: norm = dinv[i]^2
  {
    float di = dinv[wid];
    float ws = di * di;
    const float4* rs = (const float4*)(xw + (size_t)wid * D);
    #pragma unroll
    for (int v = 0; v < NV; ++v) {
      float4 xs = rs[v * 64 + lane];
      fma4(acc[v], ws, xs);
    }
  }
  if (bias) {
    #pragma unroll
    for (int v = 0; v < NV; ++v) {
      float4 b = ((const float4*)bias)[v * 64 + lane];
      acc[v].x += b.x; acc[v].y += b.y; acc[v].z += b.z; acc[v].w += b.w;
    }
  }
  float4* op = (float4*)(out + (size_t)wid * D);
  #pragma unroll
  for (int v = 0; v < NV; ++v) op[v * 64 + lane] = acc[v];
}

// ---------------- BatchNorm (training-mode batch stats) ----------------
__global__ __launch_bounds__(512) void bn_stats_k(const float* __restrict__ F,
                                                  float* __restrict__ sums, int n) {
  int t = threadIdx.x;               // column 0..511
  int r0 = blockIdx.x * 128;
  int r1 = min(r0 + 128, n);
  float s = 0.f, s2 = 0.f;
  for (int r = r0; r < r1; ++r) {
    float v = F[(size_t)r * HID + t];
    s += v;
    s2 = fmaf(v, v, s2);
  }
  atomicAdd(&sums[t], s);
  atomicAdd(&sums[HID + t], s2);
}

__global__ void bn_fin_k(const float* __restrict__ sums, const float* __restrict__ g,
                         const float* __restrict__ b, float* __restrict__ scale,
                         float* __restrict__ shift, int n) {
  int t = threadIdx.x;
  float inv = 1.0f / (float)n;
  float mu = sums[t] * inv;
  float var = fmaf(-mu, mu, sums[HID + t] * inv);  // E[x^2]-mu^2 (biased, /N)
  float rs = rsqrtf(var + 1e-5f);
  float sc = g[t] * rs;
  scale[t] = sc;
  shift[t] = fmaf(-mu, sc, b[t]);
}

// ---------------- launch ----------------
// Workspace budget:
//   d_ws : f0 (102.4 MB) + f1 (102.4 MB)                     = 204.8 MB
//   d_out: srcs/norms/cnt/cur/offs/bsum/dinv/bn scratch      =  ~13.5 MB
// d_out scratch is legal: every reader (hist..agg/bn) precedes the final
// output GEMM in stream order, and that GEMM overwrites all of d_out.
extern "C" void kernel_launch(void* const* d_in, const int* in_sizes, int n_in,
                              void* d_out, int out_size, void* d_ws, size_t ws_size,
                              hipStream_t stream) {
  const float* x     = (const float*)d_in[0];
  const int*   ei    = (const int*)d_in[1];
  const float* Wf    = (const float*)d_in[2];
  const float* bf    = (const float*)d_in[3];
  const float* Wr    = (const float*)d_in[4];
  const float* br    = (const float*)d_in[5];
  const float* gamma = (const float*)d_in[6];
  const float* beta  = (const float*)d_in[7];
  const float* Wo    = (const float*)d_in[8];
  const float* bo    = (const float*)d_in[9];
  float* out = (float*)d_out;

  const int n = in_sizes[0] / INP;
  const int E = in_sizes[1] / 2;
  const int* erow = ei;
  const int* ecol = ei + E;

  // feature ping-pong buffers in d_ws (the ONLY d_ws usage)
  char* w = (char*)d_ws;
  float* f0 = (float*)w; w += (size_t)n * HID * sizeof(float);
  float* f1 = (float*)w; w += (size_t)n * HID * sizeof(float);

  // small scratch carved from d_out (overwritten by the final GEMM at the end)
  char* q = (char*)d_out;
  int*   srcs  = (int*)q;   q += (size_t)E * sizeof(int);
  float* norms = (float*)q; q += (size_t)E * sizeof(float);
  int*   cnt   = (int*)q;   q += (size_t)n * sizeof(int);
  int*   cur   = (int*)q;   q += (size_t)n * sizeof(int);
  int*   offs  = (int*)q;   q += (size_t)n * sizeof(int);
  int*   bsum  = (int*)q;   q += 256 * sizeof(int);
  float* dinv  = (float*)q; q += (size_t)n * sizeof(float);
  float* bnsum = (float*)q; q += 1024 * sizeof(float);
  float* bnsc  = (float*)q; q += 512 * sizeof(float);
  float* bnsh  = (float*)q; q += 512 * sizeof(float);

  hipMemsetAsync(cnt, 0, (size_t)n * sizeof(int), stream);
  hipMemsetAsync(cur, 0, (size_t)n * sizeof(int), stream);

  const int eb = (E + 255) / 256;
  const int nb = (n + 255) / 256;
  hist_k<<<eb, 256, 0, stream>>>(ecol, cnt, E);
  dinv_k<<<nb, 256, 0, stream>>>(cnt, dinv, n);
  scan1_k<<<nb, 256, 0, stream>>>(cnt, offs, bsum, n);
  scan2_k<<<1, 256, 0, stream>>>(bsum, nb);
  scan3_k<<<nb, 256, 0, stream>>>(offs, bsum, n);
  scatter_k<<<eb, 256, 0, stream>>>(erow, ecol, offs, cur, dinv, srcs, norms, E);

  const dim3 blk(256);
  const int mg = (n + 127) / 128;
  const dim3 g512(mg, HID / 128);
  const dim3 g256(mg, OUTD / 128);
  const int aggBlocks = (n + 3) / 4;  // 1 wave/node, 4 waves/block

  // conv2..12: GEMM f0->f1 (prologue act), then agg f1->f0 (bias epilogue)
  auto conv = [&](const float* W, const float* b, int pro) {
    if (pro == 1)
      gemm_k<1, 0><<<g512, blk, 0, stream>>>(f0, W, f1, n, HID, HID, nullptr, nullptr, nullptr);
    else if (pro == 2)
      gemm_k<2, 0><<<g512, blk, 0, stream>>>(f0, W, f1, n, HID, HID, nullptr, bnsc, bnsh);
    else
      gemm_k<0, 0><<<g512, blk, 0, stream>>>(f0, W, f1, n, HID, HID, nullptr, nullptr, nullptr);
    agg_k<HID><<<aggBlocks, blk, 0, stream>>>(f1, srcs, norms, offs, cnt, dinv, b, f0, n);
  };
  auto bn = [&](const float* F, int g) {
    hipMemsetAsync(bnsum, 0, 1024 * sizeof(float), stream);
    bn_stats_k<<<(n + 127) / 128, 512, 0, stream>>>(F, bnsum, n);
    bn_fin_k<<<1, 512, 0, stream>>>(bnsum, gamma + (size_t)g * HID,
                                    beta + (size_t)g * HID, bnsc, bnsh, n);
  };
  const size_t WS = (size_t)HID * HID;

  // conv1 reordered: A(xW)+b == (Ax)W + b — aggregate at 256 dims first
  // (halves conv1 gather traffic), bias lands in the GEMM epilogue.
  agg_k<INP><<<aggBlocks, blk, 0, stream>>>(x, srcs, norms, offs, cnt, dinv,
                                            nullptr, f1, n);
  gemm_k<0, 1><<<g512, blk, 0, stream>>>(f1, Wf, f0, n, INP, HID, bf, nullptr, nullptr);

  conv(Wr + 0 * WS,  br + 0 * HID,  1);   // conv2
  conv(Wr + 1 * WS,  br + 1 * HID,  1);   // conv3
  conv(Wr + 2 * WS,  br + 2 * HID,  0);   // conv4 (no act)
  conv(Wr + 3 * WS,  br + 3 * HID,  1);   // conv5
  conv(Wr + 4 * WS,  br + 4 * HID,  1);   // conv6
  bn(f0, 0);                              // BN block 0
  conv(Wr + 5 * WS,  br + 5 * HID,  2);   // conv7 (bn+gelu prologue)
  conv(Wr + 6 * WS,  br + 6 * HID,  1);   // conv8
  conv(Wr + 7 * WS,  br + 7 * HID,  1);   // conv9
  bn(f0, 1);                              // BN block 1
  conv(Wr + 8 * WS,  br + 8 * HID,  2);   // conv10
  conv(Wr + 9 * WS,  br + 9 * HID,  1);   // conv11
  conv(Wr + 10 * WS, br + 10 * HID, 1);   // conv12
  gemm_k<0, 1><<<g256, blk, 0, stream>>>(f0, Wo, out, n, HID, OUTD, bo, nullptr, nullptr);
}

// Round 7
// 7420.451 us; speedup vs baseline: 1.4171x; 1.3292x over previous
//
#include <hip/hip_runtime.h>
#include <hip/hip_fp16.h>
#include <math.h>

#define INP 256
#define HID 512
#define OUTD 256

__device__ __forceinline__ float gelu_f(float x) {
  // exact (erf) GELU, matches jax.nn.gelu(approximate=False)
  return 0.5f * x * (1.0f + erff(x * 0.7071067811865475f));
}

__device__ __forceinline__ void fma4(float4& a, float w, const float4& x) {
  a.x = fmaf(w, x.x, a.x);
  a.y = fmaf(w, x.y, a.y);
  a.z = fmaf(w, x.z, a.z);
  a.w = fmaf(w, x.w, a.w);
}

// 8 halves (one float4-sized payload) -> fma into 8 fp32 accumulators
__device__ __forceinline__ void fma8h(float4& a0, float4& a1, float w,
                                      const float4& rv) {
  const __half2* h = (const __half2*)&rv;
  float2 f0 = __half22float2(h[0]);
  float2 f1 = __half22float2(h[1]);
  float2 f2 = __half22float2(h[2]);
  float2 f3 = __half22float2(h[3]);
  a0.x = fmaf(w, f0.x, a0.x); a0.y = fmaf(w, f0.y, a0.y);
  a0.z = fmaf(w, f1.x, a0.z); a0.w = fmaf(w, f1.y, a0.w);
  a1.x = fmaf(w, f2.x, a1.x); a1.y = fmaf(w, f2.y, a1.y);
  a1.z = fmaf(w, f3.x, a1.z); a1.w = fmaf(w, f3.y, a1.w);
}

// ---------------- edge preprocessing ----------------

__global__ void hist_k(const int* __restrict__ col, int* __restrict__ cnt, int E) {
  int e = blockIdx.x * blockDim.x + threadIdx.x;
  if (e < E) atomicAdd(&cnt[col[e]], 1);
}

__global__ void dinv_k(const int* __restrict__ cnt, float* __restrict__ dinv, int n) {
  int i = blockIdx.x * blockDim.x + threadIdx.x;
  if (i < n) dinv[i] = rsqrtf((float)(cnt[i] + 1));  // +1 self-loop
}

__global__ void scan1_k(const int* __restrict__ cnt, int* __restrict__ offs,
                        int* __restrict__ bsum, int n) {
  __shared__ int s[256];
  int t = threadIdx.x;
  int i = blockIdx.x * 256 + t;
  int v = (i < n) ? cnt[i] : 0;
  s[t] = v;
  __syncthreads();
  #pragma unroll
  for (int off = 1; off < 256; off <<= 1) {
    int u = (t >= off) ? s[t - off] : 0;
    __syncthreads();
    s[t] += u;
    __syncthreads();
  }
  if (i < n) offs[i] = s[t] - v;          // exclusive within block
  if (t == 255) bsum[blockIdx.x] = s[255];
}

__global__ void scan2_k(int* __restrict__ bsum, int nb) {
  __shared__ int s[256];
  int t = threadIdx.x;
  int v = (t < nb) ? bsum[t] : 0;
  s[t] = v;
  __syncthreads();
  #pragma unroll
  for (int off = 1; off < 256; off <<= 1) {
    int u = (t >= off) ? s[t - off] : 0;
    __syncthreads();
    s[t] += u;
    __syncthreads();
  }
  if (t < nb) bsum[t] = s[t] - v;         // exclusive block offsets
}

__global__ void scan3_k(int* __restrict__ offs, const int* __restrict__ bsum, int n) {
  int i = blockIdx.x * 256 + threadIdx.x;
  if (i < n) offs[i] += bsum[blockIdx.x];
}

__global__ void scatter_k(const int* __restrict__ row, const int* __restrict__ col,
                          const int* __restrict__ offs, int* __restrict__ cur,
                          const float* __restrict__ dinv, int* __restrict__ srcs,
                          float* __restrict__ norms, int E) {
  int e = blockIdx.x * blockDim.x + threadIdx.x;
  if (e >= E) return;
  int r = row[e], c = col[e];
  int p = offs[c] + atomicAdd(&cur[c], 1);
  srcs[p] = r;
  norms[p] = dinv[r] * dinv[c];
}

// ---------------- fp32 tiled GEMM, prologue act on A, optional bias ----------------
// PRO: 0 = none, 1 = GELU, 2 = BN(scale,shift)+GELU.  C = act(A) @ B [+ bias]
// HALFC: store C as fp16 (the gather payload buffer) instead of fp32.
template <int PRO, int BIAS, int HALFC>
__global__ __launch_bounds__(256) void gemm_k(
    const float* __restrict__ A, const float* __restrict__ B, void* __restrict__ Cv,
    int M, int K, int NN, const float* __restrict__ bias,
    const float* __restrict__ scale, const float* __restrict__ shift) {
  __shared__ float As[8][128];   // As[k][m] (transposed tile)
  __shared__ float Bs[8][128];
  const int t = threadIdx.x;
  const int bm = blockIdx.x * 128;
  const int bn = blockIdx.y * 128;
  const int tm = (t >> 4) << 3;          // 0..120
  const int tn = (t & 15) << 3;          // 0..120
  const int arow = t >> 1;               // 0..127
  const int acol = (t & 1) << 2;         // 0 or 4
  const int brow = t >> 5;               // 0..7
  const int bcol = (t & 31) << 2;        // 0..124
  const int gar = bm + arow;
  const bool aval = gar < M;
  const float* Ap = A + (size_t)gar * K + acol;
  const float* Bp = B + (size_t)brow * NN + bn + bcol;

  float acc[8][8];
  #pragma unroll
  for (int i = 0; i < 8; ++i)
    #pragma unroll
    for (int j = 0; j < 8; ++j) acc[i][j] = 0.f;

  for (int k0 = 0; k0 < K; k0 += 8) {
    float4 av = make_float4(0.f, 0.f, 0.f, 0.f);
    if (aval) av = *(const float4*)(Ap + k0);
    if (PRO == 2) {
      const float4 sc = *(const float4*)(scale + k0 + acol);
      const float4 sh = *(const float4*)(shift + k0 + acol);
      av.x = fmaf(av.x, sc.x, sh.x);
      av.y = fmaf(av.y, sc.y, sh.y);
      av.z = fmaf(av.z, sc.z, sh.z);
      av.w = fmaf(av.w, sc.w, sh.w);
    }
    if (PRO >= 1) {
      av.x = gelu_f(av.x); av.y = gelu_f(av.y);
      av.z = gelu_f(av.z); av.w = gelu_f(av.w);
    }
    float4 bv = *(const float4*)(Bp + (size_t)k0 * NN);
    As[acol + 0][arow] = av.x;
    As[acol + 1][arow] = av.y;
    As[acol + 2][arow] = av.z;
    As[acol + 3][arow] = av.w;
    *(float4*)(&Bs[brow][bcol]) = bv;
    __syncthreads();
    #pragma unroll
    for (int kk = 0; kk < 8; ++kk) {
      float4 a0 = *(const float4*)(&As[kk][tm]);
      float4 a1 = *(const float4*)(&As[kk][tm + 4]);
      float4 b0 = *(const float4*)(&Bs[kk][tn]);
      float4 b1 = *(const float4*)(&Bs[kk][tn + 4]);
      float a[8] = {a0.x, a0.y, a0.z, a0.w, a1.x, a1.y, a1.z, a1.w};
      float bb[8] = {b0.x, b0.y, b0.z, b0.w, b1.x, b1.y, b1.z, b1.w};
      #pragma unroll
      for (int i = 0; i < 8; ++i)
        #pragma unroll
        for (int j = 0; j < 8; ++j)
          acc[i][j] = fmaf(a[i], bb[j], acc[i][j]);
    }
    __syncthreads();
  }

  float4 c0 = make_float4(0.f, 0.f, 0.f, 0.f), c1 = c0;
  if (BIAS) {
    c0 = *(const float4*)(bias + bn + tn);
    c1 = *(const float4*)(bias + bn + tn + 4);
  }
  #pragma unroll
  for (int i = 0; i < 8; ++i) {
    int r = bm + tm + i;
    if (r < M) {
      float o[8] = {acc[i][0] + c0.x, acc[i][1] + c0.y, acc[i][2] + c0.z,
                    acc[i][3] + c0.w, acc[i][4] + c1.x, acc[i][5] + c1.y,
                    acc[i][6] + c1.z, acc[i][7] + c1.w};
      if (HALFC) {
        __half* Cp = (__half*)Cv + (size_t)r * NN + bn + tn;
        __half hv[8];
        #pragma unroll
        for (int j = 0; j < 8; ++j) hv[j] = __float2half(o[j]);
        *(float4*)Cp = *(float4*)hv;   // 8 halves = 16B store
      } else {
        float* Cp = (float*)Cv + (size_t)r * NN + bn + tn;
        *(float4*)(Cp) = make_float4(o[0], o[1], o[2], o[3]);
        *(float4*)(Cp + 4) = make_float4(o[4], o[5], o[6], o[7]);
      }
    }
  }
}

// ---------------- CSC gather aggregation (fp32 payload, conv1 only) -------------
// D = feature dim. bias==nullptr -> no bias. One wave per target node.
template <int D>
__global__ __launch_bounds__(256) void agg_k(
    const float* __restrict__ xw, const int* __restrict__ srcs,
    const float* __restrict__ norms, const int* __restrict__ offs,
    const int* __restrict__ cnt, const float* __restrict__ dinv,
    const float* __restrict__ bias, float* __restrict__ out, int n) {
  constexpr int NV = D / 256;  // float4s per lane per row
  int wid = (blockIdx.x * blockDim.x + threadIdx.x) >> 6;  // wave id = node
  int lane = threadIdx.x & 63;
  if (wid >= n) return;
  const int base = offs[wid];
  const int num = cnt[wid];

  float4 acc[NV];
  #pragma unroll
  for (int v = 0; v < NV; ++v) acc[v] = make_float4(0.f, 0.f, 0.f, 0.f);

  int sA[4], sB[4];
  float wA[4], wB[4];
  float4 rA[4][NV], rB[4][NV];

  auto ldidx = [&](int e, int& s, float& w) {
    bool ok = e < num;
    s = ok ? srcs[base + e] : 0;       // masked edges -> row 0, weight 0
    w = ok ? norms[base + e] : 0.f;
  };

  const int nw = (num + 3) >> 2;  // 4-edge windows

  if (nw > 0) {
    #pragma unroll
    for (int j = 0; j < 4; ++j) ldidx(j, sA[j], wA[j]);
    #pragma unroll
    for (int j = 0; j < 4; ++j) {
      const float4* rp = (const float4*)(xw + (size_t)sA[j] * D);
      #pragma unroll
      for (int v = 0; v < NV; ++v) rA[j][v] = rp[v * 64 + lane];
    }
    int w = 0;
    for (; w + 2 <= nw; w += 2) {
      #pragma unroll
      for (int j = 0; j < 4; ++j) ldidx((w + 1) * 4 + j, sB[j], wB[j]);
      #pragma unroll
      for (int j = 0; j < 4; ++j) {
        const float4* rp = (const float4*)(xw + (size_t)sB[j] * D);
        #pragma unroll
        for (int v = 0; v < NV; ++v) rB[j][v] = rp[v * 64 + lane];
      }
      #pragma unroll
      for (int j = 0; j < 4; ++j)
        #pragma unroll
        for (int v = 0; v < NV; ++v) fma4(acc[v], wA[j], rA[j][v]);
      if (w + 2 < nw) {
        #pragma unroll
        for (int j = 0; j < 4; ++j) ldidx((w + 2) * 4 + j, sA[j], wA[j]);
        #pragma unroll
        for (int j = 0; j < 4; ++j) {
          const float4* rp = (const float4*)(xw + (size_t)sA[j] * D);
          #pragma unroll
          for (int v = 0; v < NV; ++v) rA[j][v] = rp[v * 64 + lane];
        }
      }
      #pragma unroll
      for (int j = 0; j < 4; ++j)
        #pragma unroll
        for (int v = 0; v < NV; ++v) fma4(acc[v], wB[j], rB[j][v]);
    }
    if (w < nw) {
      #pragma unroll
      for (int j = 0; j < 4; ++j)
        #pragma unroll
        for (int v = 0; v < NV; ++v) fma4(acc[v], wA[j], rA[j][v]);
    }
  }

  {  // self loop: norm = dinv[i]^2
    float di = dinv[wid];
    float ws = di * di;
    const float4* rs = (const float4*)(xw + (size_t)wid * D);
    #pragma unroll
    for (int v = 0; v < NV; ++v) {
      float4 xs = rs[v * 64 + lane];
      fma4(acc[v], ws, xs);
    }
  }
  if (bias) {
    #pragma unroll
    for (int v = 0; v < NV; ++v) {
      float4 b = ((const float4*)bias)[v * 64 + lane];
      acc[v].x += b.x; acc[v].y += b.y; acc[v].z += b.z; acc[v].w += b.w;
    }
  }
  float4* op = (float4*)(out + (size_t)wid * D);
  #pragma unroll
  for (int v = 0; v < NV; ++v) op[v * 64 + lane] = acc[v];
}

// ---------------- CSC gather aggregation (fp16 payload, D=512) ----------------
// Lane i owns dims [8i, 8i+8): one 16B load (8 halves) per row per lane.
// fp32 accumulate; fp32 output (+bias). Register double-buffered windows.
__global__ __launch_bounds__(256) void agg_h_k(
    const __half* __restrict__ xwh, const int* __restrict__ srcs,
    const float* __restrict__ norms, const int* __restrict__ offs,
    const int* __restrict__ cnt, const float* __restrict__ dinv,
    const float* __restrict__ bias, float* __restrict__ out, int n) {
  int wid = (blockIdx.x * blockDim.x + threadIdx.x) >> 6;  // wave id = node
  int lane = threadIdx.x & 63;
  if (wid >= n) return;
  const int base = offs[wid];
  const int num = cnt[wid];

  float4 a0 = make_float4(0.f, 0.f, 0.f, 0.f);
  float4 a1 = make_float4(0.f, 0.f, 0.f, 0.f);

  int sA[4], sB[4];
  float wA[4], wB[4];
  float4 rA[4], rB[4];   // each float4 = 8 halves

  auto ldidx = [&](int e, int& s, float& w) {
    bool ok = e < num;
    s = ok ? srcs[base + e] : 0;
    w = ok ? norms[base + e] : 0.f;
  };

  const int nw = (num + 3) >> 2;

  if (nw > 0) {
    #pragma unroll
    for (int j = 0; j < 4; ++j) ldidx(j, sA[j], wA[j]);
    #pragma unroll
    for (int j = 0; j < 4; ++j)
      rA[j] = ((const float4*)(xwh + (size_t)sA[j] * HID))[lane];
    int w = 0;
    for (; w + 2 <= nw; w += 2) {
      #pragma unroll
      for (int j = 0; j < 4; ++j) ldidx((w + 1) * 4 + j, sB[j], wB[j]);
      #pragma unroll
      for (int j = 0; j < 4; ++j)
        rB[j] = ((const float4*)(xwh + (size_t)sB[j] * HID))[lane];
      #pragma unroll
      for (int j = 0; j < 4; ++j) fma8h(a0, a1, wA[j], rA[j]);
      if (w + 2 < nw) {
        #pragma unroll
        for (int j = 0; j < 4; ++j) ldidx((w + 2) * 4 + j, sA[j], wA[j]);
        #pragma unroll
        for (int j = 0; j < 4; ++j)
          rA[j] = ((const float4*)(xwh + (size_t)sA[j] * HID))[lane];
      }
      #pragma unroll
      for (int j = 0; j < 4; ++j) fma8h(a0, a1, wB[j], rB[j]);
    }
    if (w < nw) {
      #pragma unroll
      for (int j = 0; j < 4; ++j) fma8h(a0, a1, wA[j], rA[j]);
    }
  }

  {  // self loop
    float di = dinv[wid];
    float ws = di * di;
    float4 rs = ((const float4*)(xwh + (size_t)wid * HID))[lane];
    fma8h(a0, a1, ws, rs);
  }
  // bias + store: lane i owns dims [8i, 8i+8)
  const float4 b0 = *(const float4*)(bias + lane * 8);
  const float4 b1 = *(const float4*)(bias + lane * 8 + 4);
  a0.x += b0.x; a0.y += b0.y; a0.z += b0.z; a0.w += b0.w;
  a1.x += b1.x; a1.y += b1.y; a1.z += b1.z; a1.w += b1.w;
  float* op = out + (size_t)wid * HID + lane * 8;
  *(float4*)op = a0;
  *(float4*)(op + 4) = a1;
}

// ---------------- BatchNorm (training-mode batch stats) ----------------
__global__ __launch_bounds__(512) void bn_stats_k(const float* __restrict__ F,
                                                  float* __restrict__ sums, int n) {
  int t = threadIdx.x;               // column 0..511
  int r0 = blockIdx.x * 128;
  int r1 = min(r0 + 128, n);
  float s = 0.f, s2 = 0.f;
  for (int r = r0; r < r1; ++r) {
    float v = F[(size_t)r * HID + t];
    s += v;
    s2 = fmaf(v, v, s2);
  }
  atomicAdd(&sums[t], s);
  atomicAdd(&sums[HID + t], s2);
}

__global__ void bn_fin_k(const float* __restrict__ sums, const float* __restrict__ g,
                         const float* __restrict__ b, float* __restrict__ scale,
                         float* __restrict__ shift, int n) {
  int t = threadIdx.x;
  float inv = 1.0f / (float)n;
  float mu = sums[t] * inv;
  float var = fmaf(-mu, mu, sums[HID + t] * inv);  // E[x^2]-mu^2 (biased, /N)
  float rs = rsqrtf(var + 1e-5f);
  float sc = g[t] * rs;
  scale[t] = sc;
  shift[t] = fmaf(-mu, sc, b[t]);
}

// ---------------- launch ----------------
// d_ws : f0 fp32 (102.4MB) + xwh fp16 (51.2MB) + t256 fp32 (51.2MB) = 204.8MB
// d_out: srcs/norms/cnt/cur/offs/bsum/dinv/bn scratch (~13.5MB), all consumed
//        before the final output GEMM overwrites d_out.
extern "C" void kernel_launch(void* const* d_in, const int* in_sizes, int n_in,
                              void* d_out, int out_size, void* d_ws, size_t ws_size,
                              hipStream_t stream) {
  const float* x     = (const float*)d_in[0];
  const int*   ei    = (const int*)d_in[1];
  const float* Wf    = (const float*)d_in[2];
  const float* bf    = (const float*)d_in[3];
  const float* Wr    = (const float*)d_in[4];
  const float* br    = (const float*)d_in[5];
  const float* gamma = (const float*)d_in[6];
  const float* beta  = (const float*)d_in[7];
  const float* Wo    = (const float*)d_in[8];
  const float* bo    = (const float*)d_in[9];
  float* out = (float*)d_out;

  const int n = in_sizes[0] / INP;
  const int E = in_sizes[1] / 2;
  const int* erow = ei;
  const int* ecol = ei + E;

  char* w = (char*)d_ws;
  float*  f0   = (float*)w;  w += (size_t)n * HID * sizeof(float);
  __half* xwh  = (__half*)w; w += (size_t)n * HID * sizeof(__half);
  float*  t256 = (float*)w;  w += (size_t)n * INP * sizeof(float);

  char* q = (char*)d_out;
  int*   srcs  = (int*)q;   q += (size_t)E * sizeof(int);
  float* norms = (float*)q; q += (size_t)E * sizeof(float);
  int*   cnt   = (int*)q;   q += (size_t)n * sizeof(int);
  int*   cur   = (int*)q;   q += (size_t)n * sizeof(int);
  int*   offs  = (int*)q;   q += (size_t)n * sizeof(int);
  int*   bsum  = (int*)q;   q += 256 * sizeof(int);
  float* dinv  = (float*)q; q += (size_t)n * sizeof(float);
  float* bnsum = (float*)q; q += 1024 * sizeof(float);
  float* bnsc  = (float*)q; q += 512 * sizeof(float);
  float* bnsh  = (float*)q; q += 512 * sizeof(float);

  hipMemsetAsync(cnt, 0, (size_t)n * sizeof(int), stream);
  hipMemsetAsync(cur, 0, (size_t)n * sizeof(int), stream);

  const int eb = (E + 255) / 256;
  const int nb = (n + 255) / 256;
  hist_k<<<eb, 256, 0, stream>>>(ecol, cnt, E);
  dinv_k<<<nb, 256, 0, stream>>>(cnt, dinv, n);
  scan1_k<<<nb, 256, 0, stream>>>(cnt, offs, bsum, n);
  scan2_k<<<1, 256, 0, stream>>>(bsum, nb);
  scan3_k<<<nb, 256, 0, stream>>>(offs, bsum, n);
  scatter_k<<<eb, 256, 0, stream>>>(erow, ecol, offs, cur, dinv, srcs, norms, E);

  const dim3 blk(256);
  const int mg = (n + 127) / 128;
  const dim3 g512(mg, HID / 128);
  const dim3 g256(mg, OUTD / 128);
  const int aggBlocks = (n + 3) / 4;  // 1 wave/node, 4 waves/block

  // conv2..12: GEMM f0 -> xwh (fp16, prologue act), agg_h xwh -> f0 (+bias)
  auto conv = [&](const float* W, const float* b, int pro) {
    if (pro == 1)
      gemm_k<1, 0, 1><<<g512, blk, 0, stream>>>(f0, W, xwh, n, HID, HID, nullptr, nullptr, nullptr);
    else if (pro == 2)
      gemm_k<2, 0, 1><<<g512, blk, 0, stream>>>(f0, W, xwh, n, HID, HID, nullptr, bnsc, bnsh);
    else
      gemm_k<0, 0, 1><<<g512, blk, 0, stream>>>(f0, W, xwh, n, HID, HID, nullptr, nullptr, nullptr);
    agg_h_k<<<aggBlocks, blk, 0, stream>>>(xwh, srcs, norms, offs, cnt, dinv, b, f0, n);
  };
  auto bn = [&](const float* F, int g) {
    hipMemsetAsync(bnsum, 0, 1024 * sizeof(float), stream);
    bn_stats_k<<<(n + 127) / 128, 512, 0, stream>>>(F, bnsum, n);
    bn_fin_k<<<1, 512, 0, stream>>>(bnsum, gamma + (size_t)g * HID,
                                    beta + (size_t)g * HID, bnsc, bnsh, n);
  };
  const size_t WS = (size_t)HID * HID;

  // conv1 reordered: A(xW)+b == (Ax)W + b — aggregate at 256 dims first (fp32),
  // bias lands in the GEMM epilogue; GEMM writes fp32 f0.
  agg_k<INP><<<aggBlocks, blk, 0, stream>>>(x, srcs, norms, offs, cnt, dinv,
                                            nullptr, t256, n);
  gemm_k<0, 1, 0><<<g512, blk, 0, stream>>>(t256, Wf, f0, n, INP, HID, bf, nullptr, nullptr);

  conv(Wr + 0 * WS,  br + 0 * HID,  1);   // conv2
  conv(Wr + 1 * WS,  br + 1 * HID,  1);   // conv3
  conv(Wr + 2 * WS,  br + 2 * HID,  0);   // conv4 (no act)
  conv(Wr + 3 * WS,  br + 3 * HID,  1);   // conv5
  conv(Wr + 4 * WS,  br + 4 * HID,  1);   // conv6
  bn(f0, 0);                              // BN block 0
  conv(Wr + 5 * WS,  br + 5 * HID,  2);   // conv7 (bn+gelu prologue)
  conv(Wr + 6 * WS,  br + 6 * HID,  1);   // conv8
  conv(Wr + 7 * WS,  br + 7 * HID,  1);   // conv9
  bn(f0, 1);                              // BN block 1
  conv(Wr + 8 * WS,  br + 8 * HID,  2);   // conv10
  conv(Wr + 9 * WS,  br + 9 * HID,  1);   // conv11
  conv(Wr + 10 * WS, br + 10 * HID, 1);   // conv12
  gemm_k<0, 1, 0><<<g256, blk, 0, stream>>>(f0, Wo, out, n, HID, OUTD, bo, nullptr, nullptr);
}

// Round 8
// 4549.652 us; speedup vs baseline: 2.3113x; 1.6310x over previous
//
#include <hip/hip_runtime.h>
#include <hip/hip_fp16.h>
#include <math.h>

#define INP 256
#define HID 512
#define OUTD 256

typedef _Float16 f16x8 __attribute__((ext_vector_type(8)));
typedef float f32x4 __attribute__((ext_vector_type(4)));

__device__ __forceinline__ float gelu_f(float x) {
  // exact (erf) GELU, matches jax.nn.gelu(approximate=False)
  return 0.5f * x * (1.0f + erff(x * 0.7071067811865475f));
}

__device__ __forceinline__ void fma4(float4& a, float w, const float4& x) {
  a.x = fmaf(w, x.x, a.x);
  a.y = fmaf(w, x.y, a.y);
  a.z = fmaf(w, x.z, a.z);
  a.w = fmaf(w, x.w, a.w);
}

// 8 halves (one float4-sized payload) -> fma into 8 fp32 accumulators
__device__ __forceinline__ void fma8h(float4& a0, float4& a1, float w,
                                      const float4& rv) {
  const __half2* h = (const __half2*)&rv;
  float2 f0 = __half22float2(h[0]);
  float2 f1 = __half22float2(h[1]);
  float2 f2 = __half22float2(h[2]);
  float2 f3 = __half22float2(h[3]);
  a0.x = fmaf(w, f0.x, a0.x); a0.y = fmaf(w, f0.y, a0.y);
  a0.z = fmaf(w, f1.x, a0.z); a0.w = fmaf(w, f1.y, a0.w);
  a1.x = fmaf(w, f2.x, a1.x); a1.y = fmaf(w, f2.y, a1.y);
  a1.z = fmaf(w, f3.x, a1.z); a1.w = fmaf(w, f3.y, a1.w);
}

// ---------------- edge preprocessing ----------------

__global__ void hist_k(const int* __restrict__ col, int* __restrict__ cnt, int E) {
  int e = blockIdx.x * blockDim.x + threadIdx.x;
  if (e < E) atomicAdd(&cnt[col[e]], 1);
}

__global__ void dinv_k(const int* __restrict__ cnt, float* __restrict__ dinv, int n) {
  int i = blockIdx.x * blockDim.x + threadIdx.x;
  if (i < n) dinv[i] = rsqrtf((float)(cnt[i] + 1));  // +1 self-loop
}

__global__ void scan1_k(const int* __restrict__ cnt, int* __restrict__ offs,
                        int* __restrict__ bsum, int n) {
  __shared__ int s[256];
  int t = threadIdx.x;
  int i = blockIdx.x * 256 + t;
  int v = (i < n) ? cnt[i] : 0;
  s[t] = v;
  __syncthreads();
  #pragma unroll
  for (int off = 1; off < 256; off <<= 1) {
    int u = (t >= off) ? s[t - off] : 0;
    __syncthreads();
    s[t] += u;
    __syncthreads();
  }
  if (i < n) offs[i] = s[t] - v;          // exclusive within block
  if (t == 255) bsum[blockIdx.x] = s[255];
}

__global__ void scan2_k(int* __restrict__ bsum, int nb) {
  __shared__ int s[256];
  int t = threadIdx.x;
  int v = (t < nb) ? bsum[t] : 0;
  s[t] = v;
  __syncthreads();
  #pragma unroll
  for (int off = 1; off < 256; off <<= 1) {
    int u = (t >= off) ? s[t - off] : 0;
    __syncthreads();
    s[t] += u;
    __syncthreads();
  }
  if (t < nb) bsum[t] = s[t] - v;         // exclusive block offsets
}

__global__ void scan3_k(int* __restrict__ offs, const int* __restrict__ bsum, int n) {
  int i = blockIdx.x * 256 + threadIdx.x;
  if (i < n) offs[i] += bsum[blockIdx.x];
}

__global__ void scatter_k(const int* __restrict__ row, const int* __restrict__ col,
                          const int* __restrict__ offs, int* __restrict__ cur,
                          const float* __restrict__ dinv, int* __restrict__ srcs,
                          float* __restrict__ norms, int E) {
  int e = blockIdx.x * blockDim.x + threadIdx.x;
  if (e >= E) return;
  int r = row[e], c = col[e];
  int p = offs[c] + atomicAdd(&cur[c], 1);
  srcs[p] = r;
  norms[p] = dinv[r] * dinv[c];
}

// ---------------- fp16 MFMA GEMM: C = act(A_f32) @ B_f32, fp16 compute --------
// 128x128 tile, 4 waves (2x2), each wave 4x4 frags of mfma_f32_16x16x32_f16.
// LDS layout: [kchunk(8)][row][8 halves] so every ds access is a contiguous
// 16B/lane ds_*_b128 (conflict-free; round-7 VALU GEMM had 2.9e7 conflicts).
// A-frag: lane l holds A[l&15][(l>>4)*8+i]; B-frag: B[(l>>4)*8+i][l&15];
// D: col=l&15, row=(l>>4)*4+r  (m89-verified mapping).
// PRO: 0 none, 1 GELU, 2 BN+GELU (applied to A in fp32 before the cast).
template <int PRO, int BIAS, int HALFC>
__global__ __launch_bounds__(256) void gemm_k(
    const float* __restrict__ A, const float* __restrict__ B, void* __restrict__ Cv,
    int M, int K, int NN, const float* __restrict__ bias,
    const float* __restrict__ scale, const float* __restrict__ shift) {
  __shared__ f16x8 Asl[4][128];   // [k-chunk][m]
  __shared__ f16x8 Bsl[4][128];   // [k-chunk][n]
  const int t = threadIdx.x;
  const int l = t & 63, wid = t >> 6;
  const int lid = l & 15, cc = l >> 4;
  const int wr = wid >> 1, wc = wid & 1;
  const int bm = blockIdx.x * 128, bn = blockIdx.y * 128;

  // staging assignments
  const int aq = t & 3;    // A k-chunk 0..3
  const int am = t >> 2;   // A row 0..63 (+64 second half)
  const int bc = t >> 6;   // B k-chunk 0..3
  const int bn0 = t & 63;  // B col 0..63 (+64 second half)

  f32x4 acc[4][4];
  #pragma unroll
  for (int i = 0; i < 4; ++i)
    #pragma unroll
    for (int j = 0; j < 4; ++j) acc[i][j] = (f32x4)0.f;

  for (int k0 = 0; k0 < K; k0 += 32) {
    // ---- stage A (fp32 -> prologue -> fp16), coalesced 32B/thread ----
    #pragma unroll
    for (int h = 0; h < 2; ++h) {
      const int m = am + h * 64;
      const int gm = bm + m;
      const int gk = k0 + aq * 8;
      float4 v0 = make_float4(0.f, 0.f, 0.f, 0.f), v1 = v0;
      if (gm < M) {
        v0 = *(const float4*)(A + (size_t)gm * K + gk);
        v1 = *(const float4*)(A + (size_t)gm * K + gk + 4);
      }
      if (PRO == 2) {
        const float4 s0 = *(const float4*)(scale + gk);
        const float4 s1 = *(const float4*)(scale + gk + 4);
        const float4 h0 = *(const float4*)(shift + gk);
        const float4 h1 = *(const float4*)(shift + gk + 4);
        v0.x = fmaf(v0.x, s0.x, h0.x); v0.y = fmaf(v0.y, s0.y, h0.y);
        v0.z = fmaf(v0.z, s0.z, h0.z); v0.w = fmaf(v0.w, s0.w, h0.w);
        v1.x = fmaf(v1.x, s1.x, h1.x); v1.y = fmaf(v1.y, s1.y, h1.y);
        v1.z = fmaf(v1.z, s1.z, h1.z); v1.w = fmaf(v1.w, s1.w, h1.w);
      }
      if (PRO >= 1) {
        v0.x = gelu_f(v0.x); v0.y = gelu_f(v0.y);
        v0.z = gelu_f(v0.z); v0.w = gelu_f(v0.w);
        v1.x = gelu_f(v1.x); v1.y = gelu_f(v1.y);
        v1.z = gelu_f(v1.z); v1.w = gelu_f(v1.w);
      }
      f16x8 hv;
      hv[0] = (_Float16)v0.x; hv[1] = (_Float16)v0.y;
      hv[2] = (_Float16)v0.z; hv[3] = (_Float16)v0.w;
      hv[4] = (_Float16)v1.x; hv[5] = (_Float16)v1.y;
      hv[6] = (_Float16)v1.z; hv[7] = (_Float16)v1.w;
      Asl[aq][m] = hv;
    }
    // ---- stage B (weights fp32 -> fp16); per k-row lanes are coalesced ----
    #pragma unroll
    for (int h = 0; h < 2; ++h) {
      const int nn = bn0 + h * 64;
      f16x8 hv;
      #pragma unroll
      for (int j = 0; j < 8; ++j)
        hv[j] = (_Float16)B[(size_t)(k0 + bc * 8 + j) * NN + bn + nn];
      Bsl[bc][nn] = hv;
    }
    __syncthreads();
    // ---- fragments + 16 MFMA ----
    f16x8 af[4], bf[4];
    #pragma unroll
    for (int i = 0; i < 4; ++i) af[i] = Asl[cc][wr * 64 + i * 16 + lid];
    #pragma unroll
    for (int j = 0; j < 4; ++j) bf[j] = Bsl[cc][wc * 64 + j * 16 + lid];
    #pragma unroll
    for (int i = 0; i < 4; ++i)
      #pragma unroll
      for (int j = 0; j < 4; ++j)
        acc[i][j] = __builtin_amdgcn_mfma_f32_16x16x32_f16(af[i], bf[j],
                                                           acc[i][j], 0, 0, 0);
    __syncthreads();
  }

  // ---- epilogue: D col=lid, row=cc*4+r ----
  #pragma unroll
  for (int j = 0; j < 4; ++j) {
    const int col = bn + wc * 64 + j * 16 + lid;
    const float bv = BIAS ? bias[col] : 0.f;
    #pragma unroll
    for (int i = 0; i < 4; ++i) {
      #pragma unroll
      for (int r = 0; r < 4; ++r) {
        const int row = bm + wr * 64 + i * 16 + cc * 4 + r;
        if (row < M) {
          const float o = acc[i][j][r] + bv;
          if (HALFC)
            ((__half*)Cv)[(size_t)row * NN + col] = __float2half(o);
          else
            ((float*)Cv)[(size_t)row * NN + col] = o;
        }
      }
    }
  }
}

// ---------------- CSC gather aggregation (fp32 payload, conv1 only) -------------
template <int D>
__global__ __launch_bounds__(256) void agg_k(
    const float* __restrict__ xw, const int* __restrict__ srcs,
    const float* __restrict__ norms, const int* __restrict__ offs,
    const int* __restrict__ cnt, const float* __restrict__ dinv,
    const float* __restrict__ bias, float* __restrict__ out, int n) {
  constexpr int NV = D / 256;  // float4s per lane per row
  int wid = (blockIdx.x * blockDim.x + threadIdx.x) >> 6;  // wave id = node
  int lane = threadIdx.x & 63;
  if (wid >= n) return;
  const int base = offs[wid];
  const int num = cnt[wid];

  float4 acc[NV];
  #pragma unroll
  for (int v = 0; v < NV; ++v) acc[v] = make_float4(0.f, 0.f, 0.f, 0.f);

  int sA[4], sB[4];
  float wA[4], wB[4];
  float4 rA[4][NV], rB[4][NV];

  auto ldidx = [&](int e, int& s, float& w) {
    bool ok = e < num;
    s = ok ? srcs[base + e] : 0;       // masked edges -> row 0, weight 0
    w = ok ? norms[base + e] : 0.f;
  };

  const int nw = (num + 3) >> 2;  // 4-edge windows

  if (nw > 0) {
    #pragma unroll
    for (int j = 0; j < 4; ++j) ldidx(j, sA[j], wA[j]);
    #pragma unroll
    for (int j = 0; j < 4; ++j) {
      const float4* rp = (const float4*)(xw + (size_t)sA[j] * D);
      #pragma unroll
      for (int v = 0; v < NV; ++v) rA[j][v] = rp[v * 64 + lane];
    }
    int w = 0;
    for (; w + 2 <= nw; w += 2) {
      #pragma unroll
      for (int j = 0; j < 4; ++j) ldidx((w + 1) * 4 + j, sB[j], wB[j]);
      #pragma unroll
      for (int j = 0; j < 4; ++j) {
        const float4* rp = (const float4*)(xw + (size_t)sB[j] * D);
        #pragma unroll
        for (int v = 0; v < NV; ++v) rB[j][v] = rp[v * 64 + lane];
      }
      #pragma unroll
      for (int j = 0; j < 4; ++j)
        #pragma unroll
        for (int v = 0; v < NV; ++v) fma4(acc[v], wA[j], rA[j][v]);
      if (w + 2 < nw) {
        #pragma unroll
        for (int j = 0; j < 4; ++j) ldidx((w + 2) * 4 + j, sA[j], wA[j]);
        #pragma unroll
        for (int j = 0; j < 4; ++j) {
          const float4* rp = (const float4*)(xw + (size_t)sA[j] * D);
          #pragma unroll
          for (int v = 0; v < NV; ++v) rA[j][v] = rp[v * 64 + lane];
        }
      }
      #pragma unroll
      for (int j = 0; j < 4; ++j)
        #pragma unroll
        for (int v = 0; v < NV; ++v) fma4(acc[v], wB[j], rB[j][v]);
    }
    if (w < nw) {
      #pragma unroll
      for (int j = 0; j < 4; ++j)
        #pragma unroll
        for (int v = 0; v < NV; ++v) fma4(acc[v], wA[j], rA[j][v]);
    }
  }

  {  // self loop: norm = dinv[i]^2
    float di = dinv[wid];
    float ws = di * di;
    const float4* rs = (const float4*)(xw + (size_t)wid * D);
    #pragma unroll
    for (int v = 0; v < NV; ++v) {
      float4 xs = rs[v * 64 + lane];
      fma4(acc[v], ws, xs);
    }
  }
  if (bias) {
    #pragma unroll
    for (int v = 0; v < NV; ++v) {
      float4 b = ((const float4*)bias)[v * 64 + lane];
      acc[v].x += b.x; acc[v].y += b.y; acc[v].z += b.z; acc[v].w += b.w;
    }
  }
  float4* op = (float4*)(out + (size_t)wid * D);
  #pragma unroll
  for (int v = 0; v < NV; ++v) op[v * 64 + lane] = acc[v];
}

// ---------------- CSC gather aggregation (fp16 payload, D=512) ----------------
__global__ __launch_bounds__(256) void agg_h_k(
    const __half* __restrict__ xwh, const int* __restrict__ srcs,
    const float* __restrict__ norms, const int* __restrict__ offs,
    const int* __restrict__ cnt, const float* __restrict__ dinv,
    const float* __restrict__ bias, float* __restrict__ out, int n) {
  int wid = (blockIdx.x * blockDim.x + threadIdx.x) >> 6;  // wave id = node
  int lane = threadIdx.x & 63;
  if (wid >= n) return;
  const int base = offs[wid];
  const int num = cnt[wid];

  float4 a0 = make_float4(0.f, 0.f, 0.f, 0.f);
  float4 a1 = make_float4(0.f, 0.f, 0.f, 0.f);

  int sA[4], sB[4];
  float wA[4], wB[4];
  float4 rA[4], rB[4];   // each float4 = 8 halves

  auto ldidx = [&](int e, int& s, float& w) {
    bool ok = e < num;
    s = ok ? srcs[base + e] : 0;
    w = ok ? norms[base + e] : 0.f;
  };

  const int nw = (num + 3) >> 2;

  if (nw > 0) {
    #pragma unroll
    for (int j = 0; j < 4; ++j) ldidx(j, sA[j], wA[j]);
    #pragma unroll
    for (int j = 0; j < 4; ++j)
      rA[j] = ((const float4*)(xwh + (size_t)sA[j] * HID))[lane];
    int w = 0;
    for (; w + 2 <= nw; w += 2) {
      #pragma unroll
      for (int j = 0; j < 4; ++j) ldidx((w + 1) * 4 + j, sB[j], wB[j]);
      #pragma unroll
      for (int j = 0; j < 4; ++j)
        rB[j] = ((const float4*)(xwh + (size_t)sB[j] * HID))[lane];
      #pragma unroll
      for (int j = 0; j < 4; ++j) fma8h(a0, a1, wA[j], rA[j]);
      if (w + 2 < nw) {
        #pragma unroll
        for (int j = 0; j < 4; ++j) ldidx((w + 2) * 4 + j, sA[j], wA[j]);
        #pragma unroll
        for (int j = 0; j < 4; ++j)
          rA[j] = ((const float4*)(xwh + (size_t)sA[j] * HID))[lane];
      }
      #pragma unroll
      for (int j = 0; j < 4; ++j) fma8h(a0, a1, wB[j], rB[j]);
    }
    if (w < nw) {
      #pragma unroll
      for (int j = 0; j < 4; ++j) fma8h(a0, a1, wA[j], rA[j]);
    }
  }

  {  // self loop
    float di = dinv[wid];
    float ws = di * di;
    float4 rs = ((const float4*)(xwh + (size_t)wid * HID))[lane];
    fma8h(a0, a1, ws, rs);
  }
  // bias + store: lane i owns dims [8i, 8i+8)
  const float4 b0 = *(const float4*)(bias + lane * 8);
  const float4 b1 = *(const float4*)(bias + lane * 8 + 4);
  a0.x += b0.x; a0.y += b0.y; a0.z += b0.z; a0.w += b0.w;
  a1.x += b1.x; a1.y += b1.y; a1.z += b1.z; a1.w += b1.w;
  float* op = out + (size_t)wid * HID + lane * 8;
  *(float4*)op = a0;
  *(float4*)(op + 4) = a1;
}

// ---------------- BatchNorm (training-mode batch stats) ----------------
__global__ __launch_bounds__(512) void bn_stats_k(const float* __restrict__ F,
                                                  float* __restrict__ sums, int n) {
  int t = threadIdx.x;               // column 0..511
  int r0 = blockIdx.x * 128;
  int r1 = min(r0 + 128, n);
  float s = 0.f, s2 = 0.f;
  for (int r = r0; r < r1; ++r) {
    float v = F[(size_t)r * HID + t];
    s += v;
    s2 = fmaf(v, v, s2);
  }
  atomicAdd(&sums[t], s);
  atomicAdd(&sums[HID + t], s2);
}

__global__ void bn_fin_k(const float* __restrict__ sums, const float* __restrict__ g,
                         const float* __restrict__ b, float* __restrict__ scale,
                         float* __restrict__ shift, int n) {
  int t = threadIdx.x;
  float inv = 1.0f / (float)n;
  float mu = sums[t] * inv;
  float var = fmaf(-mu, mu, sums[HID + t] * inv);  // E[x^2]-mu^2 (biased, /N)
  float rs = rsqrtf(var + 1e-5f);
  float sc = g[t] * rs;
  scale[t] = sc;
  shift[t] = fmaf(-mu, sc, b[t]);
}

// ---------------- launch ----------------
// d_ws : f0 fp32 (102.4MB) + xwh fp16 (51.2MB) + t256 fp32 (51.2MB) = 204.8MB
// d_out: srcs/norms/cnt/cur/offs/bsum/dinv/bn scratch (~13.5MB), all consumed
//        before the final output GEMM overwrites d_out.
extern "C" void kernel_launch(void* const* d_in, const int* in_sizes, int n_in,
                              void* d_out, int out_size, void* d_ws, size_t ws_size,
                              hipStream_t stream) {
  const float* x     = (const float*)d_in[0];
  const int*   ei    = (const int*)d_in[1];
  const float* Wf    = (const float*)d_in[2];
  const float* bf    = (const float*)d_in[3];
  const float* Wr    = (const float*)d_in[4];
  const float* br    = (const float*)d_in[5];
  const float* gamma = (const float*)d_in[6];
  const float* beta  = (const float*)d_in[7];
  const float* Wo    = (const float*)d_in[8];
  const float* bo    = (const float*)d_in[9];
  float* out = (float*)d_out;

  const int n = in_sizes[0] / INP;
  const int E = in_sizes[1] / 2;
  const int* erow = ei;
  const int* ecol = ei + E;

  char* w = (char*)d_ws;
  float*  f0   = (float*)w;  w += (size_t)n * HID * sizeof(float);
  __half* xwh  = (__half*)w; w += (size_t)n * HID * sizeof(__half);
  float*  t256 = (float*)w;  w += (size_t)n * INP * sizeof(float);

  char* q = (char*)d_out;
  int*   srcs  = (int*)q;   q += (size_t)E * sizeof(int);
  float* norms = (float*)q; q += (size_t)E * sizeof(float);
  int*   cnt   = (int*)q;   q += (size_t)n * sizeof(int);
  int*   cur   = (int*)q;   q += (size_t)n * sizeof(int);
  int*   offs  = (int*)q;   q += (size_t)n * sizeof(int);
  int*   bsum  = (int*)q;   q += 256 * sizeof(int);
  float* dinv  = (float*)q; q += (size_t)n * sizeof(float);
  float* bnsum = (float*)q; q += 1024 * sizeof(float);
  float* bnsc  = (float*)q; q += 512 * sizeof(float);
  float* bnsh  = (float*)q; q += 512 * sizeof(float);

  hipMemsetAsync(cnt, 0, (size_t)n * sizeof(int), stream);
  hipMemsetAsync(cur, 0, (size_t)n * sizeof(int), stream);

  const int eb = (E + 255) / 256;
  const int nb = (n + 255) / 256;
  hist_k<<<eb, 256, 0, stream>>>(ecol, cnt, E);
  dinv_k<<<nb, 256, 0, stream>>>(cnt, dinv, n);
  scan1_k<<<nb, 256, 0, stream>>>(cnt, offs, bsum, n);
  scan2_k<<<1, 256, 0, stream>>>(bsum, nb);
  scan3_k<<<nb, 256, 0, stream>>>(offs, bsum, n);
  scatter_k<<<eb, 256, 0, stream>>>(erow, ecol, offs, cur, dinv, srcs, norms, E);

  const dim3 blk(256);
  const int mg = (n + 127) / 128;
  const dim3 g512(mg, HID / 128);
  const dim3 g256(mg, OUTD / 128);
  const int aggBlocks = (n + 3) / 4;  // 1 wave/node, 4 waves/block

  // conv2..12: MFMA GEMM f0 -> xwh (fp16, prologue act), agg_h xwh -> f0 (+bias)
  auto conv = [&](const float* W, const float* b, int pro) {
    if (pro == 1)
      gemm_k<1, 0, 1><<<g512, blk, 0, stream>>>(f0, W, xwh, n, HID, HID, nullptr, nullptr, nullptr);
    else if (pro == 2)
      gemm_k<2, 0, 1><<<g512, blk, 0, stream>>>(f0, W, xwh, n, HID, HID, nullptr, bnsc, bnsh);
    else
      gemm_k<0, 0, 1><<<g512, blk, 0, stream>>>(f0, W, xwh, n, HID, HID, nullptr, nullptr, nullptr);
    agg_h_k<<<aggBlocks, blk, 0, stream>>>(xwh, srcs, norms, offs, cnt, dinv, b, f0, n);
  };
  auto bn = [&](const float* F, int g) {
    hipMemsetAsync(bnsum, 0, 1024 * sizeof(float), stream);
    bn_stats_k<<<(n + 127) / 128, 512, 0, stream>>>(F, bnsum, n);
    bn_fin_k<<<1, 512, 0, stream>>>(bnsum, gamma + (size_t)g * HID,
                                    beta + (size_t)g * HID, bnsc, bnsh, n);
  };
  const size_t WS = (size_t)HID * HID;

  // conv1 reordered: A(xW)+b == (Ax)W + b — aggregate at 256 dims first (fp32),
  // bias lands in the GEMM epilogue; GEMM writes fp32 f0.
  agg_k<INP><<<aggBlocks, blk, 0, stream>>>(x, srcs, norms, offs, cnt, dinv,
                                            nullptr, t256, n);
  gemm_k<0, 1, 0><<<g512, blk, 0, stream>>>(t256, Wf, f0, n, INP, HID, bf, nullptr, nullptr);

  conv(Wr + 0 * WS,  br + 0 * HID,  1);   // conv2
  conv(Wr + 1 * WS,  br + 1 * HID,  1);   // conv3
  conv(Wr + 2 * WS,  br + 2 * HID,  0);   // conv4 (no act)
  conv(Wr + 3 * WS,  br + 3 * HID,  1);   // conv5
  conv(Wr + 4 * WS,  br + 4 * HID,  1);   // conv6
  bn(f0, 0);                              // BN block 0
  conv(Wr + 5 * WS,  br + 5 * HID,  2);   // conv7 (bn+gelu prologue)
  conv(Wr + 6 * WS,  br + 6 * HID,  1);   // conv8
  conv(Wr + 7 * WS,  br + 7 * HID,  1);   // conv9
  bn(f0, 1);                              // BN block 1
  conv(Wr + 8 * WS,  br + 8 * HID,  2);   // conv10
  conv(Wr + 9 * WS,  br + 9 * HID,  1);   // conv11
  conv(Wr + 10 * WS, br + 10 * HID, 1);   // conv12
  gemm_k<0, 1, 0><<<g256, blk, 0, stream>>>(f0, Wo, out, n, HID, OUTD, bo, nullptr, nullptr);
}

// Round 12
// 3935.614 us; speedup vs baseline: 2.6719x; 1.1560x over previous
//
#include <hip/hip_runtime.h>
#include <hip/hip_fp16.h>
#include <math.h>

#define INP 256
#define HID 512
#define OUTD 256

typedef _Float16 f16x8 __attribute__((ext_vector_type(8)));
typedef _Float16 f16x4 __attribute__((ext_vector_type(4)));
typedef float f32x4 __attribute__((ext_vector_type(4)));

__device__ __forceinline__ float gelu_f(float x) {
  // exact (erf) GELU, matches jax.nn.gelu(approximate=False)
  return 0.5f * x * (1.0f + erff(x * 0.7071067811865475f));
}

// 8 halves (float4-sized payload) -> fma into 8 fp32 accumulators
__device__ __forceinline__ void fma8h(float4& a0, float4& a1, float w,
                                      const float4& rv) {
  const __half2* h = (const __half2*)&rv;
  float2 f0 = __half22float2(h[0]);
  float2 f1 = __half22float2(h[1]);
  float2 f2 = __half22float2(h[2]);
  float2 f3 = __half22float2(h[3]);
  a0.x = fmaf(w, f0.x, a0.x); a0.y = fmaf(w, f0.y, a0.y);
  a0.z = fmaf(w, f1.x, a0.z); a0.w = fmaf(w, f1.y, a0.w);
  a1.x = fmaf(w, f2.x, a1.x); a1.y = fmaf(w, f2.y, a1.y);
  a1.z = fmaf(w, f3.x, a1.z); a1.w = fmaf(w, f3.y, a1.w);
}

// 4 halves (float2-sized payload) -> fma into 4 fp32 accumulators
__device__ __forceinline__ void fma4h(float4& a, float w, const float2& rv) {
  const __half2* h = (const __half2*)&rv;
  float2 f0 = __half22float2(h[0]);
  float2 f1 = __half22float2(h[1]);
  a.x = fmaf(w, f0.x, a.x); a.y = fmaf(w, f0.y, a.y);
  a.z = fmaf(w, f1.x, a.z); a.w = fmaf(w, f1.y, a.w);
}

// ---------------- misc ----------------

__global__ void cast16_k(const float* __restrict__ in, __half* __restrict__ o,
                         int nElem) {
  int i = (blockIdx.x * blockDim.x + threadIdx.x) * 8;
  if (i >= nElem) return;
  float4 v0 = *(const float4*)(in + i);
  float4 v1 = *(const float4*)(in + i + 4);
  f16x8 hv;
  hv[0] = (_Float16)v0.x; hv[1] = (_Float16)v0.y;
  hv[2] = (_Float16)v0.z; hv[3] = (_Float16)v0.w;
  hv[4] = (_Float16)v1.x; hv[5] = (_Float16)v1.y;
  hv[6] = (_Float16)v1.z; hv[7] = (_Float16)v1.w;
  *(f16x8*)(o + i) = hv;
}

// ---------------- edge preprocessing ----------------

__global__ void hist_k(const int* __restrict__ col, int* __restrict__ cnt, int E) {
  int e = blockIdx.x * blockDim.x + threadIdx.x;
  if (e < E) atomicAdd(&cnt[col[e]], 1);
}

__global__ void dinv_k(const int* __restrict__ cnt, float* __restrict__ dinv, int n) {
  int i = blockIdx.x * blockDim.x + threadIdx.x;
  if (i < n) dinv[i] = rsqrtf((float)(cnt[i] + 1));  // +1 self-loop
}

__global__ void scan1_k(const int* __restrict__ cnt, int* __restrict__ offs,
                        int* __restrict__ bsum, int n) {
  __shared__ int s[256];
  int t = threadIdx.x;
  int i = blockIdx.x * 256 + t;
  int v = (i < n) ? cnt[i] : 0;
  s[t] = v;
  __syncthreads();
  #pragma unroll
  for (int off = 1; off < 256; off <<= 1) {
    int u = (t >= off) ? s[t - off] : 0;
    __syncthreads();
    s[t] += u;
    __syncthreads();
  }
  if (i < n) offs[i] = s[t] - v;          // exclusive within block
  if (t == 255) bsum[blockIdx.x] = s[255];
}

__global__ void scan2_k(int* __restrict__ bsum, int nb) {
  __shared__ int s[256];
  int t = threadIdx.x;
  int v = (t < nb) ? bsum[t] : 0;
  s[t] = v;
  __syncthreads();
  #pragma unroll
  for (int off = 1; off < 256; off <<= 1) {
    int u = (t >= off) ? s[t - off] : 0;
    __syncthreads();
    s[t] += u;
    __syncthreads();
  }
  if (t < nb) bsum[t] = s[t] - v;         // exclusive block offsets
}

__global__ void scan3_k(int* __restrict__ offs, const int* __restrict__ bsum, int n) {
  int i = blockIdx.x * 256 + threadIdx.x;
  if (i < n) offs[i] += bsum[blockIdx.x];
}

__global__ void scatter_k(const int* __restrict__ row, const int* __restrict__ col,
                          const int* __restrict__ offs, int* __restrict__ cur,
                          const float* __restrict__ dinv, int* __restrict__ srcs,
                          float* __restrict__ norms, int E) {
  int e = blockIdx.x * blockDim.x + threadIdx.x;
  if (e >= E) return;
  int r = row[e], c = col[e];
  int p = offs[c] + atomicAdd(&cur[c], 1);
  srcs[p] = r;
  norms[p] = dinv[r] * dinv[c];
}

// ---------------- fp16 MFMA GEMM: C = pro(A_f16) @ B_f32 [+bias][gelu] --------
// 128x128 tile, 4 waves (2x2), 4x4 frags of mfma_f32_16x16x32_f16 per wave.
// A arrives fp16 WITH activation pre-applied by the producer (agg epilogue),
// except PRO==2 (BN scale/shift + GELU applied here, 2 convs only).
// EPI==1 applies GELU to the output (conv1's fused act for conv2).
template <int PRO, int BIAS, int HALFC, int EPI>
__global__ __launch_bounds__(256) void gemm_k(
    const __half* __restrict__ A, const float* __restrict__ B, void* __restrict__ Cv,
    int M, int K, int NN, const float* __restrict__ bias,
    const float* __restrict__ scale, const float* __restrict__ shift) {
  __shared__ f16x8 Asl[4][128];   // [k-chunk][m]
  __shared__ f16x8 Bsl[4][128];   // [k-chunk][n]
  const int t = threadIdx.x;
  const int l = t & 63, wid = t >> 6;
  const int lid = l & 15, cc = l >> 4;
  const int wr = wid >> 1, wc = wid & 1;
  const int bm = blockIdx.x * 128, bn = blockIdx.y * 128;

  const int aq = t & 3;    // A k-chunk 0..3
  const int am = t >> 2;   // A row 0..63 (+64 second half)
  const int bc = t >> 6;   // B k-chunk 0..3
  const int bn0 = t & 63;  // B col 0..63 (+64 second half)

  f32x4 acc[4][4];
  #pragma unroll
  for (int i = 0; i < 4; ++i)
    #pragma unroll
    for (int j = 0; j < 4; ++j) acc[i][j] = (f32x4)0.f;

  for (int k0 = 0; k0 < K; k0 += 32) {
    // ---- stage A (fp16 direct; PRO2: BN+GELU in fp32 then back) ----
    #pragma unroll
    for (int h = 0; h < 2; ++h) {
      const int m = am + h * 64;
      const int gm = bm + m;
      const int gk = k0 + aq * 8;
      f16x8 hv;
      if (gm < M) hv = *(const f16x8*)(A + (size_t)gm * K + gk);
      else hv = (f16x8)(_Float16)0;
      if (PRO == 2) {
        const float4 s0 = *(const float4*)(scale + gk);
        const float4 s1 = *(const float4*)(scale + gk + 4);
        const float4 h0 = *(const float4*)(shift + gk);
        const float4 h1 = *(const float4*)(shift + gk + 4);
        const float sc[8] = {s0.x, s0.y, s0.z, s0.w, s1.x, s1.y, s1.z, s1.w};
        const float sh[8] = {h0.x, h0.y, h0.z, h0.w, h1.x, h1.y, h1.z, h1.w};
        #pragma unroll
        for (int j = 0; j < 8; ++j) {
          float v = (float)hv[j];
          v = gelu_f(fmaf(v, sc[j], sh[j]));
          hv[j] = (_Float16)v;
        }
      }
      Asl[aq][m] = hv;
    }
    // ---- stage B (weights fp32 -> fp16) ----
    #pragma unroll
    for (int h = 0; h < 2; ++h) {
      const int nn = bn0 + h * 64;
      f16x8 hv;
      #pragma unroll
      for (int j = 0; j < 8; ++j)
        hv[j] = (_Float16)B[(size_t)(k0 + bc * 8 + j) * NN + bn + nn];
      Bsl[bc][nn] = hv;
    }
    __syncthreads();
    // ---- fragments + 16 MFMA ----
    f16x8 af[4], bf[4];
    #pragma unroll
    for (int i = 0; i < 4; ++i) af[i] = Asl[cc][wr * 64 + i * 16 + lid];
    #pragma unroll
    for (int j = 0; j < 4; ++j) bf[j] = Bsl[cc][wc * 64 + j * 16 + lid];
    #pragma unroll
    for (int i = 0; i < 4; ++i)
      #pragma unroll
      for (int j = 0; j < 4; ++j)
        acc[i][j] = __builtin_amdgcn_mfma_f32_16x16x32_f16(af[i], bf[j],
                                                           acc[i][j], 0, 0, 0);
    __syncthreads();
  }

  // ---- epilogue: D col=lid, row=cc*4+r ----
  #pragma unroll
  for (int j = 0; j < 4; ++j) {
    const int col = bn + wc * 64 + j * 16 + lid;
    const float bv = BIAS ? bias[col] : 0.f;
    #pragma unroll
    for (int i = 0; i < 4; ++i) {
      #pragma unroll
      for (int r = 0; r < 4; ++r) {
        const int row = bm + wr * 64 + i * 16 + cc * 4 + r;
        if (row < M) {
          float o = acc[i][j][r] + bv;
          if (EPI) o = gelu_f(o);
          if (HALFC)
            ((__half*)Cv)[(size_t)row * NN + col] = __float2half(o);
          else
            ((float*)Cv)[(size_t)row * NN + col] = o;
        }
      }
    }
  }
}

// ---------------- CSC gather aggregation (fp16 payload, D=512) ----------------
// One wave per node; lane owns dims [8l, 8l+8). Register double-buffered 4-edge
// windows keep 8 row-loads in flight. fp32 accumulate. Output fp16 = h+bias,
// optionally GELU'd (EPI=1) so the consumer GEMM reads a ready A operand.
template <int EPI>
__global__ __launch_bounds__(256) void agg512_k(
    const __half* __restrict__ xwh, const int* __restrict__ srcs,
    const float* __restrict__ norms, const int* __restrict__ offs,
    const int* __restrict__ cnt, const float* __restrict__ dinv,
    const float* __restrict__ bias, __half* __restrict__ out, int n) {
  int wid = (blockIdx.x * blockDim.x + threadIdx.x) >> 6;  // wave id = node
  int lane = threadIdx.x & 63;
  if (wid >= n) return;
  const int base = offs[wid];
  const int num = cnt[wid];

  float4 a0 = make_float4(0.f, 0.f, 0.f, 0.f);
  float4 a1 = make_float4(0.f, 0.f, 0.f, 0.f);

  int sA[4], sB[4];
  float wA[4], wB[4];
  float4 rA[4], rB[4];   // each float4 = 8 halves

  auto ldidx = [&](int e, int& s, float& w) {
    bool ok = e < num;
    s = ok ? srcs[base + e] : 0;
    w = ok ? norms[base + e] : 0.f;
  };

  const int nw = (num + 3) >> 2;

  if (nw > 0) {
    #pragma unroll
    for (int j = 0; j < 4; ++j) ldidx(j, sA[j], wA[j]);
    #pragma unroll
    for (int j = 0; j < 4; ++j)
      rA[j] = ((const float4*)(xwh + (size_t)sA[j] * HID))[lane];
    int w = 0;
    for (; w + 2 <= nw; w += 2) {
      #pragma unroll
      for (int j = 0; j < 4; ++j) ldidx((w + 1) * 4 + j, sB[j], wB[j]);
      #pragma unroll
      for (int j = 0; j < 4; ++j)
        rB[j] = ((const float4*)(xwh + (size_t)sB[j] * HID))[lane];
      #pragma unroll
      for (int j = 0; j < 4; ++j) fma8h(a0, a1, wA[j], rA[j]);
      if (w + 2 < nw) {
        #pragma unroll
        for (int j = 0; j < 4; ++j) ldidx((w + 2) * 4 + j, sA[j], wA[j]);
        #pragma unroll
        for (int j = 0; j < 4; ++j)
          rA[j] = ((const float4*)(xwh + (size_t)sA[j] * HID))[lane];
      }
      #pragma unroll
      for (int j = 0; j < 4; ++j) fma8h(a0, a1, wB[j], rB[j]);
    }
    if (w < nw) {
      #pragma unroll
      for (int j = 0; j < 4; ++j) fma8h(a0, a1, wA[j], rA[j]);
    }
  }

  {  // self loop
    float di = dinv[wid];
    float ws = di * di;
    float4 rs = ((const float4*)(xwh + (size_t)wid * HID))[lane];
    fma8h(a0, a1, ws, rs);
  }
  // bias (+gelu) + fp16 store: lane owns dims [8l, 8l+8)
  const float4 b0 = *(const float4*)(bias + lane * 8);
  const float4 b1 = *(const float4*)(bias + lane * 8 + 4);
  float o[8] = {a0.x + b0.x, a0.y + b0.y, a0.z + b0.z, a0.w + b0.w,
                a1.x + b1.x, a1.y + b1.y, a1.z + b1.z, a1.w + b1.w};
  f16x8 hv;
  #pragma unroll
  for (int j = 0; j < 8; ++j) {
    float v = EPI ? gelu_f(o[j]) : o[j];
    hv[j] = (_Float16)v;
  }
  *(f16x8*)(out + (size_t)wid * HID + lane * 8) = hv;
}

// ---------------- CSC gather aggregation (fp16, D=256, conv1) ----------------
// Lane owns dims [4l, 4l+4); 8B payloads. No bias, no act (raw Ax).
__global__ __launch_bounds__(256) void agg256_k(
    const __half* __restrict__ x16, const int* __restrict__ srcs,
    const float* __restrict__ norms, const int* __restrict__ offs,
    const int* __restrict__ cnt, const float* __restrict__ dinv,
    __half* __restrict__ out, int n) {
  int wid = (blockIdx.x * blockDim.x + threadIdx.x) >> 6;
  int lane = threadIdx.x & 63;
  if (wid >= n) return;
  const int base = offs[wid];
  const int num = cnt[wid];

  float4 a0 = make_float4(0.f, 0.f, 0.f, 0.f);

  int sA[4], sB[4];
  float wA[4], wB[4];
  float2 rA[4], rB[4];   // each float2 = 4 halves

  auto ldidx = [&](int e, int& s, float& w) {
    bool ok = e < num;
    s = ok ? srcs[base + e] : 0;
    w = ok ? norms[base + e] : 0.f;
  };

  const int nw = (num + 3) >> 2;

  if (nw > 0) {
    #pragma unroll
    for (int j = 0; j < 4; ++j) ldidx(j, sA[j], wA[j]);
    #pragma unroll
    for (int j = 0; j < 4; ++j)
      rA[j] = ((const float2*)(x16 + (size_t)sA[j] * INP))[lane];
    int w = 0;
    for (; w + 2 <= nw; w += 2) {
      #pragma unroll
      for (int j = 0; j < 4; ++j) ldidx((w + 1) * 4 + j, sB[j], wB[j]);
      #pragma unroll
      for (int j = 0; j < 4; ++j)
        rB[j] = ((const float2*)(x16 + (size_t)sB[j] * INP))[lane];
      #pragma unroll
      for (int j = 0; j < 4; ++j) fma4h(a0, wA[j], rA[j]);
      if (w + 2 < nw) {
        #pragma unroll
        for (int j = 0; j < 4; ++j) ldidx((w + 2) * 4 + j, sA[j], wA[j]);
        #pragma unroll
        for (int j = 0; j < 4; ++j)
          rA[j] = ((const float2*)(x16 + (size_t)sA[j] * INP))[lane];
      }
      #pragma unroll
      for (int j = 0; j < 4; ++j) fma4h(a0, wB[j], rB[j]);
    }
    if (w < nw) {
      #pragma unroll
      for (int j = 0; j < 4; ++j) fma4h(a0, wA[j], rA[j]);
    }
  }

  {  // self loop
    float di = dinv[wid];
    float ws = di * di;
    float2 rs = ((const float2*)(x16 + (size_t)wid * INP))[lane];
    fma4h(a0, ws, rs);
  }
  f16x4 hv;
  hv[0] = (_Float16)a0.x; hv[1] = (_Float16)a0.y;
  hv[2] = (_Float16)a0.z; hv[3] = (_Float16)a0.w;
  *(f16x4*)(out + (size_t)wid * INP + lane * 4) = hv;
}

// ---------------- BatchNorm (training-mode batch stats, fp16 input) ----------
__global__ __launch_bounds__(512) void bn_stats_h_k(const __half* __restrict__ F,
                                                    float* __restrict__ sums, int n) {
  int t = threadIdx.x;               // column 0..511
  int r0 = blockIdx.x * 128;
  int r1 = min(r0 + 128, n);
  float s = 0.f, s2 = 0.f;
  for (int r = r0; r < r1; ++r) {
    float v = __half2float(F[(size_t)r * HID + t]);
    s += v;
    s2 = fmaf(v, v, s2);
  }
  atomicAdd(&sums[t], s);
  atomicAdd(&sums[HID + t], s2);
}

__global__ void bn_fin_k(const float* __restrict__ sums, const float* __restrict__ g,
                         const float* __restrict__ b, float* __restrict__ scale,
                         float* __restrict__ shift, int n) {
  int t = threadIdx.x;
  float inv = 1.0f / (float)n;
  float mu = sums[t] * inv;
  float var = fmaf(-mu, mu, sums[HID + t] * inv);  // E[x^2]-mu^2 (biased, /N)
  float rs = rsqrtf(var + 1e-5f);
  float sc = g[t] * rs;
  scale[t] = sc;
  shift[t] = fmaf(-mu, sc, b[t]);
}

// ---------------- launch ----------------
// All-fp16 dataflow: a16 holds act-applied (or raw, where consumer needs BN/raw)
// features; xwh holds XW. No fp32 feature buffer at all.
// d_ws : a16 (51.2MB) + xwh (51.2MB) + x16 (25.6MB) + t256h (25.6MB) = 153.6MB
// d_out: edge/CSC/BN scratch (~13.5MB), all consumed before the final GEMM
//        overwrites d_out (stream-ordered).
extern "C" void kernel_launch(void* const* d_in, const int* in_sizes, int n_in,
                              void* d_out, int out_size, void* d_ws, size_t ws_size,
                              hipStream_t stream) {
  const float* x     = (const float*)d_in[0];
  const int*   ei    = (const int*)d_in[1];
  const float* Wf    = (const float*)d_in[2];
  const float* bf    = (const float*)d_in[3];
  const float* Wr    = (const float*)d_in[4];
  const float* br    = (const float*)d_in[5];
  const float* gamma = (const float*)d_in[6];
  const float* beta  = (const float*)d_in[7];
  const float* Wo    = (const float*)d_in[8];
  const float* bo    = (const float*)d_in[9];
  float* out = (float*)d_out;

  const int n = in_sizes[0] / INP;
  const int E = in_sizes[1] / 2;
  const int* erow = ei;
  const int* ecol = ei + E;

  char* w = (char*)d_ws;
  __half* a16   = (__half*)w; w += (size_t)n * HID * sizeof(__half);
  __half* xwh   = (__half*)w; w += (size_t)n * HID * sizeof(__half);
  __half* x16   = (__half*)w; w += (size_t)n * INP * sizeof(__half);
  __half* t256h = (__half*)w; w += (size_t)n * INP * sizeof(__half);

  char* q = (char*)d_out;
  int*   srcs  = (int*)q;   q += (size_t)E * sizeof(int);
  float* norms = (float*)q; q += (size_t)E * sizeof(float);
  int*   cnt   = (int*)q;   q += (size_t)n * sizeof(int);
  int*   cur   = (int*)q;   q += (size_t)n * sizeof(int);
  int*   offs  = (int*)q;   q += (size_t)n * sizeof(int);
  int*   bsum  = (int*)q;   q += 256 * sizeof(int);
  float* dinv  = (float*)q; q += (size_t)n * sizeof(float);
  float* bnsum = (float*)q; q += 1024 * sizeof(float);
  float* bnsc  = (float*)q; q += 512 * sizeof(float);
  float* bnsh  = (float*)q; q += 512 * sizeof(float);

  hipMemsetAsync(cnt, 0, (size_t)n * sizeof(int), stream);
  hipMemsetAsync(cur, 0, (size_t)n * sizeof(int), stream);

  const int eb = (E + 255) / 256;
  const int nb = (n + 255) / 256;
  cast16_k<<<(n * INP / 8 + 255) / 256, 256, 0, stream>>>(x, x16, n * INP);
  hist_k<<<eb, 256, 0, stream>>>(ecol, cnt, E);
  dinv_k<<<nb, 256, 0, stream>>>(cnt, dinv, n);
  scan1_k<<<nb, 256, 0, stream>>>(cnt, offs, bsum, n);
  scan2_k<<<1, 256, 0, stream>>>(bsum, nb);
  scan3_k<<<nb, 256, 0, stream>>>(offs, bsum, n);
  scatter_k<<<eb, 256, 0, stream>>>(erow, ecol, offs, cur, dinv, srcs, norms, E);

  const dim3 blk(256);
  const int mg = (n + 127) / 128;
  const dim3 g512(mg, HID / 128);
  const dim3 g256(mg, OUTD / 128);
  const int aggBlocks = (n + 3) / 4;  // 1 wave/node, 4 waves/block

  // conv_i (i>=2): GEMM a16 -> xwh, then agg xwh -> a16 with the NEXT conv's
  // activation applied (epi=1: gelu; epi=0: raw, consumer does BN or nothing).
  auto conv = [&](const float* W, const float* b, int pro, int epi) {
    if (pro == 2)
      gemm_k<2, 0, 1, 0><<<g512, blk, 0, stream>>>(a16, W, xwh, n, HID, HID, nullptr, bnsc, bnsh);
    else
      gemm_k<0, 0, 1, 0><<<g512, blk, 0, stream>>>(a16, W, xwh, n, HID, HID, nullptr, nullptr, nullptr);
    if (epi)
      agg512_k<1><<<aggBlocks, blk, 0, stream>>>(xwh, srcs, norms, offs, cnt, dinv, b, a16, n);
    else
      agg512_k<0><<<aggBlocks, blk, 0, stream>>>(xwh, srcs, norms, offs, cnt, dinv, b, a16, n);
  };
  auto bn = [&](int g) {
    hipMemsetAsync(bnsum, 0, 1024 * sizeof(float), stream);
    bn_stats_h_k<<<(n + 127) / 128, 512, 0, stream>>>(a16, bnsum, n);
    bn_fin_k<<<1, 512, 0, stream>>>(bnsum, gamma + (size_t)g * HID,
                                    beta + (size_t)g * HID, bnsc, bnsh, n);
  };
  const size_t WS = (size_t)HID * HID;

  // conv1 reordered: h1 = (Ax)W + bf; epilogue applies conv2's GELU.
  agg256_k<<<aggBlocks, blk, 0, stream>>>(x16, srcs, norms, offs, cnt, dinv,
                                          t256h, n);
  gemm_k<0, 1, 1, 1><<<g512, blk, 0, stream>>>(t256h, Wf, a16, n, INP, HID, bf, nullptr, nullptr);

  conv(Wr + 0 * WS,  br + 0 * HID,  0, 1);   // conv2  -> gelu (conv3)
  conv(Wr + 1 * WS,  br + 1 * HID,  0, 0);   // conv3  -> raw  (conv4 no act)
  conv(Wr + 2 * WS,  br + 2 * HID,  0, 1);   // conv4  -> gelu (conv5)
  conv(Wr + 3 * WS,  br + 3 * HID,  0, 1);   // conv5  -> gelu (conv6)
  conv(Wr + 4 * WS,  br + 4 * HID,  0, 0);   // conv6  -> raw  (BN block 0)
  bn(0);
  conv(Wr + 5 * WS,  br + 5 * HID,  2, 1);   // conv7  (BN+GELU prologue) -> gelu
  conv(Wr + 6 * WS,  br + 6 * HID,  0, 1);   // conv8  -> gelu (conv9)
  conv(Wr + 7 * WS,  br + 7 * HID,  0, 0);   // conv9  -> raw  (BN block 1)
  bn(1);
  conv(Wr + 8 * WS,  br + 8 * HID,  2, 1);   // conv10 (BN+GELU prologue) -> gelu
  conv(Wr + 9 * WS,  br + 9 * HID,  0, 1);   // conv11 -> gelu (conv12)
  conv(Wr + 10 * WS, br + 10 * HID, 0, 0);   // conv12 -> raw  (out proj)
  gemm_k<0, 1, 0, 0><<<g256, blk, 0, stream>>>(a16, Wo, out, n, HID, OUTD, bo, nullptr, nullptr);
}